// Round 5
// baseline (76827.502 us; speedup 1.0000x reference)
//
#include <hip/hip_runtime.h>
#include <hip/hip_bf16.h>
#include <math.h>

// R20: occupancy fix. Numerics BIT-IDENTICAL to R17/R19.
// Diagnosis (R17-R19 counters): conv grids were 256-512 blocks = 1-2
// blocks/CU -> every stage round exposes global latency with no TLP cover;
// VALUBusy pinned 22-53%, occupancy 12-25%.
// Fix:
//  - conv_tiled<NW>: waves/block template. 64x64 convs use NW=2 (128 thr),
//    COB 16 (res1 8) -> grids 2048-4096 = 8-16 blocks/CU, 16-32 waves/CU.
//    Per-thread work/registers unchanged (CPW=8 path = verified 84-VGPR code).
//  - deconv1w: 1-wave blocks, 8x8 input positions, no barriers; dt1 grid
//    16384. CQ=8 (dt1) / 3 (dt2).
//  - NCI reduced so LDS 2-17KB never caps residency.
// All per-output fma chains (ci,kh,kw asc; deconv tap order) untouched.
// Pipeline: fp64 encoder -> fp32 z, np-exact fp32 VQ, straight-through
// fl(z+fl(q-z)), fp32 decoder, fp32 output writes.

template<typename T> __device__ __forceinline__ T fmaT(T a, T b, T c);
template<> __device__ __forceinline__ double fmaT(double a, double b, double c) { return fma(a, b, c); }
template<> __device__ __forceinline__ float  fmaT(float a, float b, float c)    { return fmaf(a, b, c); }
template<typename T> __device__ __forceinline__ T maxT(T a, T b);
template<> __device__ __forceinline__ double maxT(double a, double b) { return fmax(a, b); }
template<> __device__ __forceinline__ float  maxT(float a, float b)   { return fmaxf(a, b); }

// ---------------------------------------------------------------------------
// LDS-tiled conv. NW waves/block; 16x16 output tile x COB couts. Each wave
// covers the full tile (4 pix/lane) for its CPW=COB/NW couts. Single-buffer
// stage -> barrier -> compute. Rows padded +1. Accumulation per output:
// ci asc, kh asc, kw asc — bit-identical to the direct kernels.
// ---------------------------------------------------------------------------
template<typename TIn, typename TAcc, typename TOut, int K, int S, int PAD,
         bool IN_RELU, bool OUT_RELU, bool RES_ADD, int NCI, int COB, int NW>
__global__ __launch_bounds__(NW * 64, 8)
void conv_tiled(const TIn* __restrict__ in, const float* __restrict__ w,
                const float* __restrict__ bias, const TAcc* __restrict__ res,
                TOut* __restrict__ out,
                int B, int Cin, int Hin, int Win, int Cout, int Hout, int Wout)
{
    constexpr int NT   = NW * 64;
    constexpr int TILE = 16;
    constexpr int IT   = (TILE - 1) * S + K;   // input tile edge incl. halo
    constexpr int ITT  = IT * IT;
    constexpr int RS   = IT + 1;               // padded row stride
    constexpr int CSZ  = IT * RS;
    constexpr int NEL  = NCI * ITT;
    constexpr int CPW  = COB / NW;
    constexpr int PIX  = 4;
    constexpr int WIN  = (PIX - 1) * S + K;

    __shared__ TAcc tile[NCI * CSZ];

    int ntx = Wout / TILE, nty = Hout / TILE, ncb = Cout / COB;
    int g = blockIdx.x;
    int tx = g % ntx; g /= ntx;
    int ty = g % nty; g /= nty;
    int cb = g % ncb;
    int b  = g / ncb;

    int t    = threadIdx.x;
    int wave = t >> 6;
    int lane = t & 63;
    int lowg = lane & 3;
    int loh  = lane >> 2;                      // 0..15
    int co0  = cb * COB + wave * CPW;
    int oh0t = ty * TILE, ow0t = tx * TILE;
    int oh   = oh0t + loh;
    int ow0  = ow0t + lowg * PIX;

    TAcc acc[CPW][PIX];
    #pragma unroll
    for (int c = 0; c < CPW; c++) {
        TAcc bv = (TAcc)bias[co0 + c];
        #pragma unroll
        for (int j = 0; j < PIX; j++) acc[c][j] = bv;
    }

    const int ihb = oh0t * S - PAD;
    const int iwb = ow0t * S - PAD;
    const long inHW = (long)Hin * Win;
    const int KK  = K * K;
    const int wCK = Cin * KK;

    for (int ci0 = 0; ci0 < Cin; ci0 += NCI) {
        __syncthreads();
        for (int e = t; e < NEL; e += NT) {
            int c = e / ITT, rm = e - c * ITT;
            int rr = rm / IT, cc = rm - rr * IT;
            int ih = ihb + rr, iw = iwb + cc;
            TAcc v = (TAcc)0;
            if ((unsigned)ih < (unsigned)Hin && (unsigned)iw < (unsigned)Win)
                v = (TAcc)in[((long)b * Cin + ci0 + c) * inHW + (long)ih * Win + iw];
            if (IN_RELU) v = maxT(v, (TAcc)0);
            tile[c * CSZ + rr * RS + cc] = v;
        }
        __syncthreads();
        #pragma unroll
        for (int c = 0; c < NCI; c++) {
            const float* wp = w + ((long)co0 * Cin + (ci0 + c)) * KK;
            #pragma unroll
            for (int kh = 0; kh < K; kh++) {
                const TAcc* rp = tile + c * CSZ + (loh * S + kh) * RS + lowg * PIX * S;
                TAcc iv[WIN];
                #pragma unroll
                for (int x = 0; x < WIN; x++) iv[x] = rp[x];
                #pragma unroll
                for (int c2 = 0; c2 < CPW; c2++) {
                    #pragma unroll
                    for (int kw = 0; kw < K; kw++) {
                        TAcc wv = (TAcc)wp[c2 * wCK + kh * K + kw];
                        #pragma unroll
                        for (int j = 0; j < PIX; j++)
                            acc[c2][j] = fmaT(iv[j * S + kw], wv, acc[c2][j]);
                    }
                }
            }
        }
    }

    long ostride = (long)Hout * Wout;
    long obase = (((long)b * Cout + co0) * Hout + oh) * Wout + ow0;
    #pragma unroll
    for (int c = 0; c < CPW; c++) {
        #pragma unroll
        for (int j = 0; j < PIX; j++) {
            TAcc v = acc[c][j];
            if (RES_ADD) v += res[obase + c * ostride + j];
            if (OUT_RELU) v = maxT(v, (TAcc)0);
            out[obase + c * ostride + j] = (TOut)v;
        }
    }
}

// ---------------------------------------------------------------------------
// 1-wave LDS-tiled ConvTranspose2d k=4 s=2 p=1, fp32. 64 threads own an 8x8
// input tile (10x10 halo in LDS, padded rows); each thread computes its 2x2
// output quad for CQ couts. No cross-wave barriers. Per-output fmaf chains
// replicate the original deconv exactly:
//   even oh: kh=1 (row iy) then kh=3 (row iy-1); odd oh: kh=0 (iy+1), kh=2 (iy)
//   even ow: +i[iw-1]*w[kh][3] then +i[iw]*w[kh][1]
//   odd  ow: +i[iw]*w[kh][2]  then +i[iw+1]*w[kh][0]
// ---------------------------------------------------------------------------
template<int CQ, bool IN_RELU, bool OUT_RELU, bool OUT_TANH, int NCI>
__global__ __launch_bounds__(64, 8)
void deconv1w(const float* __restrict__ in, const float* __restrict__ w,
              const float* __restrict__ bias, float* __restrict__ out,
              int B, int Cin, int Hin, int Win, int Cout)
{
    constexpr int IT  = 10;          // 8 + 2 halo
    constexpr int ITT = IT * IT;
    constexpr int RS  = IT + 1;
    constexpr int CSZ = IT * RS;
    constexpr int NEL = NCI * ITT;
    int Hout = Hin << 1, Wout = Win << 1;

    __shared__ float tile[NCI * CSZ];

    int ntx = Win >> 3, nty = Hin >> 3, ncb = Cout / CQ;
    int g = blockIdx.x;
    int tx = g % ntx; g /= ntx;
    int ty = g % nty; g /= nty;
    int cb = g % ncb;
    int b  = g / ncb;

    int t   = threadIdx.x;
    int tix = t & 7;
    int tiy = t >> 3;                // 0..7
    int ix0 = tx << 3, iy0 = ty << 3;
    int co0 = cb * CQ;

    float acc[CQ][4];
    #pragma unroll
    for (int c = 0; c < CQ; c++) {
        float bv = bias[co0 + c];
        #pragma unroll
        for (int j = 0; j < 4; j++) acc[c][j] = bv;
    }

    const long inHW = (long)Hin * Win;

    for (int ci0 = 0; ci0 < Cin; ci0 += NCI) {
        __syncthreads();
        for (int e = t; e < NEL; e += 64) {
            int c = e / ITT, rm = e - c * ITT;
            int rr = rm / IT, cc = rm - rr * IT;
            int ih = iy0 - 1 + rr, iw = ix0 - 1 + cc;
            float v = 0.f;
            if ((unsigned)ih < (unsigned)Hin && (unsigned)iw < (unsigned)Win)
                v = in[((long)b * Cin + ci0 + c) * inHW + (long)ih * Win + iw];
            if (IN_RELU) v = fmaxf(v, 0.f);
            tile[c * CSZ + rr * RS + cc] = v;
        }
        __syncthreads();
        #pragma unroll
        for (int c = 0; c < NCI; c++) {
            const float* tp = tile + c * CSZ + tiy * RS + tix;
            float n00 = tp[0],        n01 = tp[1],          n02 = tp[2];
            float n10 = tp[RS],       n11 = tp[RS + 1],     n12 = tp[RS + 2];
            float n20 = tp[2 * RS],   n21 = tp[2 * RS + 1], n22 = tp[2 * RS + 2];
            const float* wb = w + ((long)(ci0 + c) * Cout + co0) * 16;
            #pragma unroll
            for (int cq = 0; cq < CQ; cq++) {
                const float* wk = wb + cq * 16;
                float a0 = acc[cq][0], a1 = acc[cq][1];
                float a2 = acc[cq][2], a3 = acc[cq][3];
                a0 = fmaf(n11, wk[5],  fmaf(n10, wk[7],  a0));
                a0 = fmaf(n01, wk[13], fmaf(n00, wk[15], a0));
                a1 = fmaf(n12, wk[4],  fmaf(n11, wk[6],  a1));
                a1 = fmaf(n02, wk[12], fmaf(n01, wk[14], a1));
                a2 = fmaf(n21, wk[1],  fmaf(n20, wk[3],  a2));
                a2 = fmaf(n11, wk[9],  fmaf(n10, wk[11], a2));
                a3 = fmaf(n22, wk[0],  fmaf(n21, wk[2],  a3));
                a3 = fmaf(n12, wk[8],  fmaf(n11, wk[10], a3));
                acc[cq][0] = a0; acc[cq][1] = a1;
                acc[cq][2] = a2; acc[cq][3] = a3;
            }
        }
    }

    int oh0 = (iy0 + tiy) << 1;
    int ow0 = (ix0 + tix) << 1;
    long ostride = (long)Hout * Wout;
    long obase = (((long)b * Cout + co0) * Hout + oh0) * Wout + ow0;
    #pragma unroll
    for (int c = 0; c < CQ; c++) {
        #pragma unroll
        for (int j = 0; j < 4; j++) {
            float v = acc[c][j];
            if (OUT_RELU) v = fmaxf(v, 0.f);
            if (OUT_TANH) v = tanhf(v);
            out[obase + c * ostride + (j >> 1) * (long)Wout + (j & 1)] = v;
        }
    }
}

// numpy pairwise sum-of-squares over 64 fp32 values.
__device__ __forceinline__ float np_sumsq64(const float* v) {
    float r[8];
    #pragma unroll
    for (int j = 0; j < 8; j++) r[j] = __fmul_rn(v[j], v[j]);
    #pragma unroll
    for (int i = 8; i < 64; i += 8) {
        #pragma unroll
        for (int j = 0; j < 8; j++)
            r[j] = __fadd_rn(r[j], __fmul_rn(v[i + j], v[i + j]));
    }
    float s01 = __fadd_rn(r[0], r[1]), s23 = __fadd_rn(r[2], r[3]);
    float s45 = __fadd_rn(r[4], r[5]), s67 = __fadd_rn(r[6], r[7]);
    return __fadd_rn(__fadd_rn(s01, s23), __fadd_rn(s45, s67));
}

__global__ void codenorm_kernel(const float* __restrict__ cb, float* __restrict__ cn)
{
    int k = blockIdx.x * 64 + threadIdx.x;
    if (k >= 512) return;
    float row[64];
    #pragma unroll
    for (int d = 0; d < 64; d++) row[d] = cb[k * 64 + d];
    cn[k] = np_sumsq64(row);
}

// VQ: np-exact fp32 chain; st = fl(z + fl(q-z)).
__global__ __launch_bounds__(256)
void vq_kernel(const float* __restrict__ z, const float* __restrict__ cb,
               const float* __restrict__ cn, float* __restrict__ st,
               double* __restrict__ loss_sum, int B)
{
    __shared__ float zt[64][256];
    int t = threadIdx.x;
    long pg = (long)blockIdx.x * 256;
    int b = (int)(pg >> 12);
    int p0 = (int)(pg & 4095);
    const float* zb = z + (long)b * 64 * 4096 + p0;
    #pragma unroll
    for (int d = 0; d < 64; d++) zt[d][t] = zb[(long)d * 4096 + t];
    __syncthreads();

    int p = p0 + t;
    float zr[64];
    #pragma unroll
    for (int d = 0; d < 64; d++) zr[d] = zt[d][t];

    float s1 = np_sumsq64(zr);

    float best = INFINITY;
    int bi = 0;
    for (int k = 0; k < 512; k += 4) {
        const float* c0 = cb + (k + 0) * 64;
        const float* c1 = cb + (k + 1) * 64;
        const float* c2 = cb + (k + 2) * 64;
        const float* c3 = cb + (k + 3) * 64;
        float m0 = 0.f, m1 = 0.f, m2 = 0.f, m3 = 0.f;
        #pragma unroll
        for (int d = 0; d < 64; d++) {
            float zd = zr[d];
            m0 = fmaf(zd, c0[d], m0);
            m1 = fmaf(zd, c1[d], m1);
            m2 = fmaf(zd, c2[d], m2);
            m3 = fmaf(zd, c3[d], m3);
        }
        float d0 = __fadd_rn(__fsub_rn(s1, __fmul_rn(2.f, m0)), cn[k + 0]);
        float d1 = __fadd_rn(__fsub_rn(s1, __fmul_rn(2.f, m1)), cn[k + 1]);
        float d2 = __fadd_rn(__fsub_rn(s1, __fmul_rn(2.f, m2)), cn[k + 2]);
        float d3 = __fadd_rn(__fsub_rn(s1, __fmul_rn(2.f, m3)), cn[k + 3]);
        if (d0 < best) { best = d0; bi = k + 0; }
        if (d1 < best) { best = d1; bi = k + 1; }
        if (d2 < best) { best = d2; bi = k + 2; }
        if (d3 < best) { best = d3; bi = k + 3; }
    }

    const float* cbest = cb + bi * 64;
    float* sp = st + (long)b * 64 * 4096 + p;
    double ls = 0.0;
    #pragma unroll
    for (int d = 0; d < 64; d++) {
        float qv = cbest[d];
        float zv = zr[d];
        float diff = __fsub_rn(qv, zv);
        double dd = (double)qv - (double)zv;
        ls += dd * dd;
        sp[(long)d * 4096] = __fadd_rn(zv, diff);
    }
    #pragma unroll
    for (int off = 32; off > 0; off >>= 1) ls += __shfl_down(ls, off, 64);
    if ((t & 63) == 0) atomicAdd(loss_sum, ls);
}

__global__ void loss_final_kernel(const double* __restrict__ s, float* __restrict__ out)
{
    out[0] = (float)(1.25 * s[0] / 8388608.0);   // fp32 loss store
}

extern "C" void kernel_launch(void* const* d_in, const int* in_sizes, int n_in,
                              void* d_out, int out_size, void* d_ws, size_t ws_size,
                              hipStream_t stream)
{
    const float* x        = (const float*)d_in[0];
    const float* enc_w1   = (const float*)d_in[1];
    const float* enc_b1   = (const float*)d_in[2];
    const float* enc_w2   = (const float*)d_in[3];
    const float* enc_b2   = (const float*)d_in[4];
    const float* enc_w3   = (const float*)d_in[5];
    const float* enc_b3   = (const float*)d_in[6];
    const float* enc_rw1  = (const float*)d_in[7];
    const float* enc_rb1  = (const float*)d_in[8];
    const float* enc_rw2  = (const float*)d_in[9];
    const float* enc_rb2  = (const float*)d_in[10];
    const float* pvq_w    = (const float*)d_in[11];
    const float* pvq_b    = (const float*)d_in[12];
    const float* codebook = (const float*)d_in[13];
    const float* dec_w1   = (const float*)d_in[14];
    const float* dec_b1   = (const float*)d_in[15];
    const float* dec_rw1  = (const float*)d_in[16];
    const float* dec_rb1  = (const float*)d_in[17];
    const float* dec_rw2  = (const float*)d_in[18];
    const float* dec_rb2  = (const float*)d_in[19];
    const float* dt1_w    = (const float*)d_in[20];
    const float* dt1_b    = (const float*)d_in[21];
    const float* dt2_w    = (const float*)d_in[22];
    const float* dt2_b    = (const float*)d_in[23];

    float* out = (float*)d_out;            // fp32 output buffer (ref dtype)
    char* wsb = (char*)d_ws;

    float*  CN = (float*)wsb;              // 512 floats
    double* LS = (double*)(wsb + 4096);    // 1 double
    const size_t SMALLB = 4352;

    const long eA = 1048576, eB = 524288, eC = 524288, eT = 131072;
    const long eZ = 262144, eQ = 262144;
    const size_t perSampleB = (size_t)(eA + eB + eC + eT) * 8 + (size_t)(eZ + eQ) * 4;

    int Bc = 32;
    while (Bc > 1 && SMALLB + perSampleB * Bc + 1024 > ws_size) Bc >>= 1;
    const int nChunks = 32 / Bc;

    double* A64 = (double*)(wsb + SMALLB);
    double* B64 = A64 + eA * Bc;
    double* C64 = B64 + eB * Bc;
    double* T64 = C64 + eC * Bc;
    float*  Z32 = (float*)(T64 + eT * Bc);
    float*  Qf  = Z32 + eZ * Bc;
    float* Df = (float*)B64;   // decoder fp32 aliases (encoder buffers dead)
    float* Tf = (float*)T64;
    float* Ef = (float*)A64;

    hipMemsetAsync(LS, 0, sizeof(double), stream);
    codenorm_kernel<<<8, 64, 0, stream>>>(codebook, CN);

    for (int c = 0; c < nChunks; c++) {
        const float* xc = x + (long)c * Bc * 3 * 65536;
        float* outc = out + (long)c * Bc * 3 * 65536;

        // ---- encoder (fp64 accumulate -> fp32 z) ----
        // enc1: 4x4 s2 3->64, 256->128, OUT_RELU. NW=4, grid 4096.
        conv_tiled<float,double,double,4,2,1,false,true,false,3,32,4>
            <<<Bc*8*8*2, 256, 0, stream>>>(
            xc, enc_w1, enc_b1, nullptr, A64, Bc, 3, 256, 256, 64, 128, 128);
        // enc2: 4x4 s2 64->128, 128->64, OUT_RELU. NW=2 COB=16 NCI=1: grid 4096.
        conv_tiled<double,double,double,4,2,1,false,true,false,1,16,2>
            <<<Bc*4*4*8, 128, 0, stream>>>(
            A64, enc_w2, enc_b2, nullptr, B64, Bc, 64, 128, 128, 128, 64, 64);
        // enc3: 3x3 s1 128->128. NW=2 COB=16 NCI=2: grid 4096.
        conv_tiled<double,double,double,3,1,1,false,false,false,2,16,2>
            <<<Bc*4*4*8, 128, 0, stream>>>(
            B64, enc_w3, enc_b3, nullptr, C64, Bc, 128, 64, 64, 128, 64, 64);
        for (int i = 0; i < 2; i++) {
            // res1: 3x3 128->32, IN_RELU. NW=2 COB=8 NCI=2: grid 2048.
            conv_tiled<double,double,double,3,1,1,true,false,false,2,8,2>
                <<<Bc*4*4*4, 128, 0, stream>>>(
                C64, enc_rw1 + (long)i*32*128*9, enc_rb1 + i*32, nullptr, T64,
                Bc, 128, 64, 64, 32, 64, 64);
            // res2: 1x1 32->128, IN_RELU, +residual C64. NW=2 COB=16 NCI=8: grid 4096.
            conv_tiled<double,double,double,1,1,0,true,false,true,8,16,2>
                <<<Bc*4*4*8, 128, 0, stream>>>(
                T64, enc_rw2 + (long)i*128*32, enc_rb2 + i*128, C64, C64,
                Bc, 32, 64, 64, 128, 64, 64);
        }
        // pvq: 1x1 128->64, IN_RELU, fp32 store. NW=2 COB=16 NCI=8: grid 2048.
        conv_tiled<double,double,float,1,1,0,true,false,false,8,16,2>
            <<<Bc*4*4*4, 128, 0, stream>>>(
            C64, pvq_w, pvq_b, nullptr, Z32, Bc, 128, 64, 64, 64, 64, 64);

        // ---- VQ (np-exact fp32) ----
        vq_kernel<<<Bc * 16, 256, 0, stream>>>(Z32, codebook, CN, Qf, LS, Bc);

        // ---- decoder (fp32), fp32 output stores ----
        conv_tiled<float,float,float,3,1,1,false,false,false,4,16,2>
            <<<Bc*4*4*8, 128, 0, stream>>>(
            Qf, dec_w1, dec_b1, nullptr, Df, Bc, 64, 64, 64, 128, 64, 64);
        for (int i = 0; i < 2; i++) {
            conv_tiled<float,float,float,3,1,1,true,false,false,4,8,2>
                <<<Bc*4*4*4, 128, 0, stream>>>(
                Df, dec_rw1 + (long)i*32*128*9, dec_rb1 + i*32, nullptr, Tf,
                Bc, 128, 64, 64, 32, 64, 64);
            conv_tiled<float,float,float,1,1,0,true,false,true,8,16,2>
                <<<Bc*4*4*8, 128, 0, stream>>>(
                Tf, dec_rw2 + (long)i*128*32, dec_rb2 + i*128, Df, Df,
                Bc, 32, 64, 64, 128, 64, 64);
        }
        // dt1: deconv 128->64, 64->128, IN_RELU + OUT_RELU. 1-wave, grid 16384.
        deconv1w<8,true,true,false,4><<<Bc*8*8*8, 64, 0, stream>>>(
            Df, dt1_w, dt1_b, Ef, Bc, 128, 64, 64, 64);
        // dt2: deconv 64->3, 128->256, tanh. 1-wave, grid 8192.
        deconv1w<3,false,false,true,8><<<Bc*16*16*1, 64, 0, stream>>>(
            Ef, dt2_w, dt2_b, outc, Bc, 64, 128, 128, 3);
    }

    loss_final_kernel<<<1, 1, 0, stream>>>(LS, out + 6291456);
}

// Round 6
// 6903.381 us; speedup vs baseline: 11.1290x; 11.1290x over previous
//
#include <hip/hip_runtime.h>
#include <hip/hip_bf16.h>
#include <math.h>

// R21: occupancy via workspace aliasing. Numerics BIT-IDENTICAL to R17.
// R20 post-mortem: __launch_bounds__(...,8) capped VGPR at 32 -> total spill
// (24 GB scratch writes/dispatch). Reverted to the verified 84-VGPR regime.
// R17 counters prove Bc=8 (FETCH 62.8MB = one Bc=8 input read) -> grids were
// 512-1024 blocks = 2-4 blocks/CU: THE occupancy cap all along.
// Fixes (no computed bit changes):
//  - Buffer aliasing: A64 region (dead after enc2) hosts C64/T64/Z32/Qf/Ef;
//    B64 region (dead after enc3) hosts Df/Tf. 19.9 -> 12 MB/sample => Bc=16
//    (auto-halving keeps correctness for any ws_size).
//  - LDS row padding +1 (R19-verified bit-safe): kills the 1.05e7
//    bank-conflict cycles on the fp64 ds_reads.
//  - fp32 decoder COB 16/8 (CPW 4/2): more blocks, fewer VGPRs.
// Pipeline: fp64 encoder -> fp32 z, np-exact fp32 VQ, straight-through
// fl(z+fl(q-z)), fp32 decoder, fp32 output writes.

template<typename T> __device__ __forceinline__ T fmaT(T a, T b, T c);
template<> __device__ __forceinline__ double fmaT(double a, double b, double c) { return fma(a, b, c); }
template<> __device__ __forceinline__ float  fmaT(float a, float b, float c)    { return fmaf(a, b, c); }
template<typename T> __device__ __forceinline__ T maxT(T a, T b);
template<> __device__ __forceinline__ double maxT(double a, double b) { return fmax(a, b); }
template<> __device__ __forceinline__ float  maxT(float a, float b)   { return fmaxf(a, b); }

// ---------------------------------------------------------------------------
// LDS-tiled conv. 256 threads = 4 waves; 16x16 output tile x COB couts.
// Single-buffer stage -> barrier -> compute. Rows padded +1 (bank spread).
// Accumulation per output: ci asc, kh asc, kw asc — bit-identical to direct.
// ---------------------------------------------------------------------------
template<typename TIn, typename TAcc, typename TOut, int K, int S, int PAD,
         bool IN_RELU, bool OUT_RELU, bool RES_ADD, int NCI, int COB>
__global__ __launch_bounds__(256, 3)
void conv_tiled(const TIn* __restrict__ in, const float* __restrict__ w,
                const float* __restrict__ bias, const TAcc* __restrict__ res,
                TOut* __restrict__ out,
                int B, int Cin, int Hin, int Win, int Cout, int Hout, int Wout)
{
    constexpr int TILE = 16;
    constexpr int IT   = (TILE - 1) * S + K;   // input tile edge incl. halo
    constexpr int ITT  = IT * IT;
    constexpr int RS   = IT + 1;               // padded row stride
    constexpr int CSZ  = IT * RS;
    constexpr int NEL  = NCI * ITT;
    constexpr int CPW  = COB / 4;
    constexpr int PIX  = 4;
    constexpr int WIN  = (PIX - 1) * S + K;

    __shared__ TAcc tile[NCI * CSZ];

    int ntx = Wout / TILE, nty = Hout / TILE, ncb = Cout / COB;
    int g = blockIdx.x;
    int tx = g % ntx; g /= ntx;
    int ty = g % nty; g /= nty;
    int cb = g % ncb;
    int b  = g / ncb;

    int t    = threadIdx.x;
    int wave = t >> 6;
    int lowg = t & 3;
    int loh  = (t >> 2) & 15;
    int co0  = cb * COB + wave * CPW;
    int oh0t = ty * TILE, ow0t = tx * TILE;
    int oh   = oh0t + loh;
    int ow0  = ow0t + lowg * PIX;

    TAcc acc[CPW][PIX];
    #pragma unroll
    for (int c = 0; c < CPW; c++) {
        TAcc bv = (TAcc)bias[co0 + c];
        #pragma unroll
        for (int j = 0; j < PIX; j++) acc[c][j] = bv;
    }

    const int ihb = oh0t * S - PAD;
    const int iwb = ow0t * S - PAD;
    const long inHW = (long)Hin * Win;
    const int KK  = K * K;
    const int wCK = Cin * KK;

    for (int ci0 = 0; ci0 < Cin; ci0 += NCI) {
        __syncthreads();
        for (int e = t; e < NEL; e += 256) {
            int c = e / ITT, rm = e - c * ITT;
            int rr = rm / IT, cc = rm - rr * IT;
            int ih = ihb + rr, iw = iwb + cc;
            TAcc v = (TAcc)0;
            if ((unsigned)ih < (unsigned)Hin && (unsigned)iw < (unsigned)Win)
                v = (TAcc)in[((long)b * Cin + ci0 + c) * inHW + (long)ih * Win + iw];
            if (IN_RELU) v = maxT(v, (TAcc)0);
            tile[c * CSZ + rr * RS + cc] = v;
        }
        __syncthreads();
        #pragma unroll
        for (int c = 0; c < NCI; c++) {
            const float* wp = w + ((long)co0 * Cin + (ci0 + c)) * KK;
            #pragma unroll
            for (int kh = 0; kh < K; kh++) {
                const TAcc* rp = tile + c * CSZ + (loh * S + kh) * RS + lowg * PIX * S;
                TAcc iv[WIN];
                #pragma unroll
                for (int x = 0; x < WIN; x++) iv[x] = rp[x];
                #pragma unroll
                for (int c2 = 0; c2 < CPW; c2++) {
                    #pragma unroll
                    for (int kw = 0; kw < K; kw++) {
                        TAcc wv = (TAcc)wp[c2 * wCK + kh * K + kw];
                        #pragma unroll
                        for (int j = 0; j < PIX; j++)
                            acc[c2][j] = fmaT(iv[j * S + kw], wv, acc[c2][j]);
                    }
                }
            }
        }
    }

    long ostride = (long)Hout * Wout;
    long obase = (((long)b * Cout + co0) * Hout + oh) * Wout + ow0;
    #pragma unroll
    for (int c = 0; c < CPW; c++) {
        #pragma unroll
        for (int j = 0; j < PIX; j++) {
            TAcc v = acc[c][j];
            if (RES_ADD) v += res[obase + c * ostride + j];
            if (OUT_RELU) v = maxT(v, (TAcc)0);
            out[obase + c * ostride + j] = (TOut)v;
        }
    }
}

// ---------------------------------------------------------------------------
// LDS-tiled ConvTranspose2d k=4 s=2 p=1, fp32, 4-wave blocks, padded rows.
// Each thread owns input pos (tiy,tix) of a 16x16 tile (18x18 halo in LDS)
// and computes its 2x2 output quad for CQ couts. Per-output fmaf chains
// replicate the original deconv exactly:
//   even oh: kh=1 (row iy) then kh=3 (row iy-1); odd oh: kh=0 (iy+1), kh=2 (iy)
//   even ow: +i[iw-1]*w[kh][3] then +i[iw]*w[kh][1]
//   odd  ow: +i[iw]*w[kh][2]  then +i[iw+1]*w[kh][0]
// ---------------------------------------------------------------------------
template<int CQ, bool IN_RELU, bool OUT_RELU, bool OUT_TANH, int NCI>
__global__ __launch_bounds__(256, 3)
void deconv_tiled(const float* __restrict__ in, const float* __restrict__ w,
                  const float* __restrict__ bias, float* __restrict__ out,
                  int B, int Cin, int Hin, int Win, int Cout)
{
    constexpr int IT  = 18;          // 16 + 2 halo
    constexpr int ITT = IT * IT;
    constexpr int RS  = IT + 1;
    constexpr int CSZ = IT * RS;
    constexpr int NEL = NCI * ITT;
    int Hout = Hin << 1, Wout = Win << 1;

    __shared__ float tile[NCI * CSZ];

    int ntx = Win >> 4, nty = Hin >> 4, ncb = Cout / CQ;
    int g = blockIdx.x;
    int tx = g % ntx; g /= ntx;
    int ty = g % nty; g /= nty;
    int cb = g % ncb;
    int b  = g / ncb;

    int t   = threadIdx.x;
    int tix = t & 15;
    int tiy = t >> 4;
    int ix0 = tx << 4, iy0 = ty << 4;
    int co0 = cb * CQ;

    float acc[CQ][4];
    #pragma unroll
    for (int c = 0; c < CQ; c++) {
        float bv = bias[co0 + c];
        #pragma unroll
        for (int j = 0; j < 4; j++) acc[c][j] = bv;
    }

    const long inHW = (long)Hin * Win;

    for (int ci0 = 0; ci0 < Cin; ci0 += NCI) {
        __syncthreads();
        for (int e = t; e < NEL; e += 256) {
            int c = e / ITT, rm = e - c * ITT;
            int rr = rm / IT, cc = rm - rr * IT;
            int ih = iy0 - 1 + rr, iw = ix0 - 1 + cc;
            float v = 0.f;
            if ((unsigned)ih < (unsigned)Hin && (unsigned)iw < (unsigned)Win)
                v = in[((long)b * Cin + ci0 + c) * inHW + (long)ih * Win + iw];
            if (IN_RELU) v = fmaxf(v, 0.f);
            tile[c * CSZ + rr * RS + cc] = v;
        }
        __syncthreads();
        #pragma unroll
        for (int c = 0; c < NCI; c++) {
            const float* tp = tile + c * CSZ + tiy * RS + tix;
            float n00 = tp[0],        n01 = tp[1],          n02 = tp[2];
            float n10 = tp[RS],       n11 = tp[RS + 1],     n12 = tp[RS + 2];
            float n20 = tp[2 * RS],   n21 = tp[2 * RS + 1], n22 = tp[2 * RS + 2];
            const float* wb = w + ((long)(ci0 + c) * Cout + co0) * 16;
            #pragma unroll
            for (int cq = 0; cq < CQ; cq++) {
                const float* wk = wb + cq * 16;
                float a0 = acc[cq][0], a1 = acc[cq][1];
                float a2 = acc[cq][2], a3 = acc[cq][3];
                a0 = fmaf(n11, wk[5],  fmaf(n10, wk[7],  a0));
                a0 = fmaf(n01, wk[13], fmaf(n00, wk[15], a0));
                a1 = fmaf(n12, wk[4],  fmaf(n11, wk[6],  a1));
                a1 = fmaf(n02, wk[12], fmaf(n01, wk[14], a1));
                a2 = fmaf(n21, wk[1],  fmaf(n20, wk[3],  a2));
                a2 = fmaf(n11, wk[9],  fmaf(n10, wk[11], a2));
                a3 = fmaf(n22, wk[0],  fmaf(n21, wk[2],  a3));
                a3 = fmaf(n12, wk[8],  fmaf(n11, wk[10], a3));
                acc[cq][0] = a0; acc[cq][1] = a1;
                acc[cq][2] = a2; acc[cq][3] = a3;
            }
        }
    }

    int oh0 = (iy0 + tiy) << 1;
    int ow0 = (ix0 + tix) << 1;
    long ostride = (long)Hout * Wout;
    long obase = (((long)b * Cout + co0) * Hout + oh0) * Wout + ow0;
    #pragma unroll
    for (int c = 0; c < CQ; c++) {
        #pragma unroll
        for (int j = 0; j < 4; j++) {
            float v = acc[c][j];
            if (OUT_RELU) v = fmaxf(v, 0.f);
            if (OUT_TANH) v = tanhf(v);
            out[obase + c * ostride + (j >> 1) * (long)Wout + (j & 1)] = v;
        }
    }
}

// numpy pairwise sum-of-squares over 64 fp32 values.
__device__ __forceinline__ float np_sumsq64(const float* v) {
    float r[8];
    #pragma unroll
    for (int j = 0; j < 8; j++) r[j] = __fmul_rn(v[j], v[j]);
    #pragma unroll
    for (int i = 8; i < 64; i += 8) {
        #pragma unroll
        for (int j = 0; j < 8; j++)
            r[j] = __fadd_rn(r[j], __fmul_rn(v[i + j], v[i + j]));
    }
    float s01 = __fadd_rn(r[0], r[1]), s23 = __fadd_rn(r[2], r[3]);
    float s45 = __fadd_rn(r[4], r[5]), s67 = __fadd_rn(r[6], r[7]);
    return __fadd_rn(__fadd_rn(s01, s23), __fadd_rn(s45, s67));
}

__global__ void codenorm_kernel(const float* __restrict__ cb, float* __restrict__ cn)
{
    int k = blockIdx.x * 64 + threadIdx.x;
    if (k >= 512) return;
    float row[64];
    #pragma unroll
    for (int d = 0; d < 64; d++) row[d] = cb[k * 64 + d];
    cn[k] = np_sumsq64(row);
}

// VQ: np-exact fp32 chain; st = fl(z + fl(q-z)).
__global__ __launch_bounds__(256)
void vq_kernel(const float* __restrict__ z, const float* __restrict__ cb,
               const float* __restrict__ cn, float* __restrict__ st,
               double* __restrict__ loss_sum, int B)
{
    __shared__ float zt[64][256];
    int t = threadIdx.x;
    long pg = (long)blockIdx.x * 256;
    int b = (int)(pg >> 12);
    int p0 = (int)(pg & 4095);
    const float* zb = z + (long)b * 64 * 4096 + p0;
    #pragma unroll
    for (int d = 0; d < 64; d++) zt[d][t] = zb[(long)d * 4096 + t];
    __syncthreads();

    int p = p0 + t;
    float zr[64];
    #pragma unroll
    for (int d = 0; d < 64; d++) zr[d] = zt[d][t];

    float s1 = np_sumsq64(zr);

    float best = INFINITY;
    int bi = 0;
    for (int k = 0; k < 512; k += 4) {
        const float* c0 = cb + (k + 0) * 64;
        const float* c1 = cb + (k + 1) * 64;
        const float* c2 = cb + (k + 2) * 64;
        const float* c3 = cb + (k + 3) * 64;
        float m0 = 0.f, m1 = 0.f, m2 = 0.f, m3 = 0.f;
        #pragma unroll
        for (int d = 0; d < 64; d++) {
            float zd = zr[d];
            m0 = fmaf(zd, c0[d], m0);
            m1 = fmaf(zd, c1[d], m1);
            m2 = fmaf(zd, c2[d], m2);
            m3 = fmaf(zd, c3[d], m3);
        }
        float d0 = __fadd_rn(__fsub_rn(s1, __fmul_rn(2.f, m0)), cn[k + 0]);
        float d1 = __fadd_rn(__fsub_rn(s1, __fmul_rn(2.f, m1)), cn[k + 1]);
        float d2 = __fadd_rn(__fsub_rn(s1, __fmul_rn(2.f, m2)), cn[k + 2]);
        float d3 = __fadd_rn(__fsub_rn(s1, __fmul_rn(2.f, m3)), cn[k + 3]);
        if (d0 < best) { best = d0; bi = k + 0; }
        if (d1 < best) { best = d1; bi = k + 1; }
        if (d2 < best) { best = d2; bi = k + 2; }
        if (d3 < best) { best = d3; bi = k + 3; }
    }

    const float* cbest = cb + bi * 64;
    float* sp = st + (long)b * 64 * 4096 + p;
    double ls = 0.0;
    #pragma unroll
    for (int d = 0; d < 64; d++) {
        float qv = cbest[d];
        float zv = zr[d];
        float diff = __fsub_rn(qv, zv);
        double dd = (double)qv - (double)zv;
        ls += dd * dd;
        sp[(long)d * 4096] = __fadd_rn(zv, diff);
    }
    #pragma unroll
    for (int off = 32; off > 0; off >>= 1) ls += __shfl_down(ls, off, 64);
    if ((t & 63) == 0) atomicAdd(loss_sum, ls);
}

__global__ void loss_final_kernel(const double* __restrict__ s, float* __restrict__ out)
{
    out[0] = (float)(1.25 * s[0] / 8388608.0);   // fp32 loss store
}

extern "C" void kernel_launch(void* const* d_in, const int* in_sizes, int n_in,
                              void* d_out, int out_size, void* d_ws, size_t ws_size,
                              hipStream_t stream)
{
    const float* x        = (const float*)d_in[0];
    const float* enc_w1   = (const float*)d_in[1];
    const float* enc_b1   = (const float*)d_in[2];
    const float* enc_w2   = (const float*)d_in[3];
    const float* enc_b2   = (const float*)d_in[4];
    const float* enc_w3   = (const float*)d_in[5];
    const float* enc_b3   = (const float*)d_in[6];
    const float* enc_rw1  = (const float*)d_in[7];
    const float* enc_rb1  = (const float*)d_in[8];
    const float* enc_rw2  = (const float*)d_in[9];
    const float* enc_rb2  = (const float*)d_in[10];
    const float* pvq_w    = (const float*)d_in[11];
    const float* pvq_b    = (const float*)d_in[12];
    const float* codebook = (const float*)d_in[13];
    const float* dec_w1   = (const float*)d_in[14];
    const float* dec_b1   = (const float*)d_in[15];
    const float* dec_rw1  = (const float*)d_in[16];
    const float* dec_rb1  = (const float*)d_in[17];
    const float* dec_rw2  = (const float*)d_in[18];
    const float* dec_rb2  = (const float*)d_in[19];
    const float* dt1_w    = (const float*)d_in[20];
    const float* dt1_b    = (const float*)d_in[21];
    const float* dt2_w    = (const float*)d_in[22];
    const float* dt2_b    = (const float*)d_in[23];

    float* out = (float*)d_out;            // fp32 output buffer (ref dtype)
    char* wsb = (char*)d_ws;

    float*  CN = (float*)wsb;              // 512 floats
    double* LS = (double*)(wsb + 4096);    // 1 double
    const size_t SMALLB = 4352;

    // Aliased layout, 12 MB/sample:
    //  P region (8MB/s): A64 (enc1 out, dead after enc2) -> C64(4MB) T64(1MB)
    //                    Z32(1MB) Qf(1MB); Ef(4MB, after C64/T64/Z32 dead)
    //  Q region (4MB/s): B64 (enc2 out, dead after enc3) -> Df(2MB) Tf(0.5MB)
    const size_t perSampleB = 12582912;    // 8MB + 4MB

    int Bc = 32;
    while (Bc > 1 && SMALLB + perSampleB * Bc + 1024 > ws_size) Bc >>= 1;
    const int nChunks = 32 / Bc;

    char* base  = wsb + SMALLB;
    char* qbase = base + (size_t)Bc * 8388608;
    double* A64 = (double*)base;                              // Bc x 1048576 d
    double* C64 = (double*)base;                              // Bc x 524288 d
    double* T64 = (double*)(base + (size_t)Bc * 4194304);     // Bc x 131072 d
    float*  Z32 = (float*)(base + (size_t)Bc * 5242880);      // Bc x 262144 f
    float*  Qf  = (float*)(base + (size_t)Bc * 6291456);      // Bc x 262144 f
    float*  Ef  = (float*)base;                               // Bc x 1048576 f
    double* B64 = (double*)qbase;                             // Bc x 524288 d
    float*  Df  = (float*)qbase;                              // Bc x 524288 f
    float*  Tf  = (float*)(qbase + (size_t)Bc * 2097152);     // Bc x 131072 f

    hipMemsetAsync(LS, 0, sizeof(double), stream);
    codenorm_kernel<<<8, 64, 0, stream>>>(codebook, CN);

    for (int c = 0; c < nChunks; c++) {
        const float* xc = x + (long)c * Bc * 3 * 65536;
        float* outc = out + (long)c * Bc * 3 * 65536;

        // ---- encoder (fp64 accumulate -> fp32 z) ----
        // enc1: 4x4 s2 3->64, 256->128, OUT_RELU.
        conv_tiled<float,double,double,4,2,1,false,true,false,3,32>
            <<<Bc*8*8*2, 256, 0, stream>>>(
            xc, enc_w1, enc_b1, nullptr, A64, Bc, 3, 256, 256, 64, 128, 128);
        // enc2: 4x4 s2 64->128, 128->64, OUT_RELU. Reads A64, writes B64.
        conv_tiled<double,double,double,4,2,1,false,true,false,2,32>
            <<<Bc*4*4*4, 256, 0, stream>>>(
            A64, enc_w2, enc_b2, nullptr, B64, Bc, 64, 128, 128, 128, 64, 64);
        // enc3: 3x3 s1 128->128. Reads B64, writes C64 (A64 dead).
        conv_tiled<double,double,double,3,1,1,false,false,false,4,32>
            <<<Bc*4*4*4, 256, 0, stream>>>(
            B64, enc_w3, enc_b3, nullptr, C64, Bc, 128, 64, 64, 128, 64, 64);
        for (int i = 0; i < 2; i++) {
            // res1: 3x3 128->32, IN_RELU.
            conv_tiled<double,double,double,3,1,1,true,false,false,8,16>
                <<<Bc*4*4*2, 256, 0, stream>>>(
                C64, enc_rw1 + (long)i*32*128*9, enc_rb1 + i*32, nullptr, T64,
                Bc, 128, 64, 64, 32, 64, 64);
            // res2: 1x1 32->128, IN_RELU, +residual C64, in-place.
            conv_tiled<double,double,double,1,1,0,true,false,true,16,32>
                <<<Bc*4*4*4, 256, 0, stream>>>(
                T64, enc_rw2 + (long)i*128*32, enc_rb2 + i*128, C64, C64,
                Bc, 32, 64, 64, 128, 64, 64);
        }
        // pvq: 1x1 128->64, IN_RELU, fp32 store.
        conv_tiled<double,double,float,1,1,0,true,false,false,16,32>
            <<<Bc*4*4*2, 256, 0, stream>>>(
            C64, pvq_w, pvq_b, nullptr, Z32, Bc, 128, 64, 64, 64, 64, 64);

        // ---- VQ (np-exact fp32) ----
        vq_kernel<<<Bc * 16, 256, 0, stream>>>(Z32, codebook, CN, Qf, LS, Bc);

        // ---- decoder (fp32), fp32 output stores ----
        // dec1: 3x3 64->128. Reads Qf, writes Df (B64 dead).
        conv_tiled<float,float,float,3,1,1,false,false,false,8,16>
            <<<Bc*4*4*8, 256, 0, stream>>>(
            Qf, dec_w1, dec_b1, nullptr, Df, Bc, 64, 64, 64, 128, 64, 64);
        for (int i = 0; i < 2; i++) {
            conv_tiled<float,float,float,3,1,1,true,false,false,8,8>
                <<<Bc*4*4*4, 256, 0, stream>>>(
                Df, dec_rw1 + (long)i*32*128*9, dec_rb1 + i*32, nullptr, Tf,
                Bc, 128, 64, 64, 32, 64, 64);
            conv_tiled<float,float,float,1,1,0,true,false,true,16,16>
                <<<Bc*4*4*8, 256, 0, stream>>>(
                Tf, dec_rw2 + (long)i*128*32, dec_rb2 + i*128, Df, Df,
                Bc, 32, 64, 64, 128, 64, 64);
        }
        // dt1: deconv 128->64, 64->128, IN_RELU + OUT_RELU. Writes Ef
        // (C64/T64/Z32 dead; Qf untouched at +6MB).
        deconv_tiled<8,true,true,false,8><<<Bc*4*4*8, 256, 0, stream>>>(
            Df, dt1_w, dt1_b, Ef, Bc, 128, 64, 64, 64);
        // dt2: deconv 64->3, 128->256, tanh, writes final output.
        deconv_tiled<3,false,false,true,8><<<Bc*8*8*1, 256, 0, stream>>>(
            Ef, dt2_w, dt2_b, outc, Bc, 64, 128, 128, 3);
    }

    loss_final_kernel<<<1, 1, 0, stream>>>(LS, out + 6291456);
}

// Round 7
// 6812.287 us; speedup vs baseline: 11.2778x; 1.0134x over previous
//
#include <hip/hip_runtime.h>
#include <hip/hip_bf16.h>
#include <math.h>

// R22: grid doubling via COB halving + 4-way VQ split. Numerics BIT-IDENTICAL.
// R21 post-mortem: enc2 at 4 blocks/CU (grid 1024) while VGPR allows 6, LDS 8
// -> still grid-limited (occupancy 27%, VALUBusy 55%, 62% of fp64 FMA floor).
// Padding kept but conflicts were only ~5% of cycles — grid was the lever.
// Changes (block decomposition only; per-output fma chains untouched):
//  - enc2/enc3 COB 32->16 (grid 2048 = 8 blk/CU; CPW 4 -> fp64 acc 32 VGPR)
//  - res1 COB 16->8 (grid 1024); res2/pvq COB 16, NCI 8
//  - VQ: 64 px/block, 4 threads/px scanning disjoint ascending k-quarters,
//    strict-< LDS merge (== single ascending strict-< scan; lowest-k ties).
//    Grid 256 -> 1024 blocks.
// Pipeline: fp64 encoder -> fp32 z, np-exact fp32 VQ, straight-through
// fl(z+fl(q-z)), fp32 decoder, fp32 output writes.

template<typename T> __device__ __forceinline__ T fmaT(T a, T b, T c);
template<> __device__ __forceinline__ double fmaT(double a, double b, double c) { return fma(a, b, c); }
template<> __device__ __forceinline__ float  fmaT(float a, float b, float c)    { return fmaf(a, b, c); }
template<typename T> __device__ __forceinline__ T maxT(T a, T b);
template<> __device__ __forceinline__ double maxT(double a, double b) { return fmax(a, b); }
template<> __device__ __forceinline__ float  maxT(float a, float b)   { return fmaxf(a, b); }

// ---------------------------------------------------------------------------
// LDS-tiled conv. 256 threads = 4 waves; 16x16 output tile x COB couts.
// Single-buffer stage -> barrier -> compute. Rows padded +1.
// Accumulation per output: ci asc, kh asc, kw asc — bit-identical to direct.
// ---------------------------------------------------------------------------
template<typename TIn, typename TAcc, typename TOut, int K, int S, int PAD,
         bool IN_RELU, bool OUT_RELU, bool RES_ADD, int NCI, int COB>
__global__ __launch_bounds__(256, 3)
void conv_tiled(const TIn* __restrict__ in, const float* __restrict__ w,
                const float* __restrict__ bias, const TAcc* __restrict__ res,
                TOut* __restrict__ out,
                int B, int Cin, int Hin, int Win, int Cout, int Hout, int Wout)
{
    constexpr int TILE = 16;
    constexpr int IT   = (TILE - 1) * S + K;   // input tile edge incl. halo
    constexpr int ITT  = IT * IT;
    constexpr int RS   = IT + 1;               // padded row stride
    constexpr int CSZ  = IT * RS;
    constexpr int NEL  = NCI * ITT;
    constexpr int CPW  = COB / 4;
    constexpr int PIX  = 4;
    constexpr int WIN  = (PIX - 1) * S + K;

    __shared__ TAcc tile[NCI * CSZ];

    int ntx = Wout / TILE, nty = Hout / TILE, ncb = Cout / COB;
    int g = blockIdx.x;
    int tx = g % ntx; g /= ntx;
    int ty = g % nty; g /= nty;
    int cb = g % ncb;
    int b  = g / ncb;

    int t    = threadIdx.x;
    int wave = t >> 6;
    int lowg = t & 3;
    int loh  = (t >> 2) & 15;
    int co0  = cb * COB + wave * CPW;
    int oh0t = ty * TILE, ow0t = tx * TILE;
    int oh   = oh0t + loh;
    int ow0  = ow0t + lowg * PIX;

    TAcc acc[CPW][PIX];
    #pragma unroll
    for (int c = 0; c < CPW; c++) {
        TAcc bv = (TAcc)bias[co0 + c];
        #pragma unroll
        for (int j = 0; j < PIX; j++) acc[c][j] = bv;
    }

    const int ihb = oh0t * S - PAD;
    const int iwb = ow0t * S - PAD;
    const long inHW = (long)Hin * Win;
    const int KK  = K * K;
    const int wCK = Cin * KK;

    for (int ci0 = 0; ci0 < Cin; ci0 += NCI) {
        __syncthreads();
        for (int e = t; e < NEL; e += 256) {
            int c = e / ITT, rm = e - c * ITT;
            int rr = rm / IT, cc = rm - rr * IT;
            int ih = ihb + rr, iw = iwb + cc;
            TAcc v = (TAcc)0;
            if ((unsigned)ih < (unsigned)Hin && (unsigned)iw < (unsigned)Win)
                v = (TAcc)in[((long)b * Cin + ci0 + c) * inHW + (long)ih * Win + iw];
            if (IN_RELU) v = maxT(v, (TAcc)0);
            tile[c * CSZ + rr * RS + cc] = v;
        }
        __syncthreads();
        #pragma unroll
        for (int c = 0; c < NCI; c++) {
            const float* wp = w + ((long)co0 * Cin + (ci0 + c)) * KK;
            #pragma unroll
            for (int kh = 0; kh < K; kh++) {
                const TAcc* rp = tile + c * CSZ + (loh * S + kh) * RS + lowg * PIX * S;
                TAcc iv[WIN];
                #pragma unroll
                for (int x = 0; x < WIN; x++) iv[x] = rp[x];
                #pragma unroll
                for (int c2 = 0; c2 < CPW; c2++) {
                    #pragma unroll
                    for (int kw = 0; kw < K; kw++) {
                        TAcc wv = (TAcc)wp[c2 * wCK + kh * K + kw];
                        #pragma unroll
                        for (int j = 0; j < PIX; j++)
                            acc[c2][j] = fmaT(iv[j * S + kw], wv, acc[c2][j]);
                    }
                }
            }
        }
    }

    long ostride = (long)Hout * Wout;
    long obase = (((long)b * Cout + co0) * Hout + oh) * Wout + ow0;
    #pragma unroll
    for (int c = 0; c < CPW; c++) {
        #pragma unroll
        for (int j = 0; j < PIX; j++) {
            TAcc v = acc[c][j];
            if (RES_ADD) v += res[obase + c * ostride + j];
            if (OUT_RELU) v = maxT(v, (TAcc)0);
            out[obase + c * ostride + j] = (TOut)v;
        }
    }
}

// ---------------------------------------------------------------------------
// LDS-tiled ConvTranspose2d k=4 s=2 p=1, fp32, 4-wave blocks, padded rows.
// Each thread owns input pos (tiy,tix) of a 16x16 tile (18x18 halo in LDS)
// and computes its 2x2 output quad for CQ couts. Per-output fmaf chains
// replicate the original deconv exactly:
//   even oh: kh=1 (row iy) then kh=3 (row iy-1); odd oh: kh=0 (iy+1), kh=2 (iy)
//   even ow: +i[iw-1]*w[kh][3] then +i[iw]*w[kh][1]
//   odd  ow: +i[iw]*w[kh][2]  then +i[iw+1]*w[kh][0]
// ---------------------------------------------------------------------------
template<int CQ, bool IN_RELU, bool OUT_RELU, bool OUT_TANH, int NCI>
__global__ __launch_bounds__(256, 3)
void deconv_tiled(const float* __restrict__ in, const float* __restrict__ w,
                  const float* __restrict__ bias, float* __restrict__ out,
                  int B, int Cin, int Hin, int Win, int Cout)
{
    constexpr int IT  = 18;          // 16 + 2 halo
    constexpr int ITT = IT * IT;
    constexpr int RS  = IT + 1;
    constexpr int CSZ = IT * RS;
    constexpr int NEL = NCI * ITT;
    int Hout = Hin << 1, Wout = Win << 1;

    __shared__ float tile[NCI * CSZ];

    int ntx = Win >> 4, nty = Hin >> 4, ncb = Cout / CQ;
    int g = blockIdx.x;
    int tx = g % ntx; g /= ntx;
    int ty = g % nty; g /= nty;
    int cb = g % ncb;
    int b  = g / ncb;

    int t   = threadIdx.x;
    int tix = t & 15;
    int tiy = t >> 4;
    int ix0 = tx << 4, iy0 = ty << 4;
    int co0 = cb * CQ;

    float acc[CQ][4];
    #pragma unroll
    for (int c = 0; c < CQ; c++) {
        float bv = bias[co0 + c];
        #pragma unroll
        for (int j = 0; j < 4; j++) acc[c][j] = bv;
    }

    const long inHW = (long)Hin * Win;

    for (int ci0 = 0; ci0 < Cin; ci0 += NCI) {
        __syncthreads();
        for (int e = t; e < NEL; e += 256) {
            int c = e / ITT, rm = e - c * ITT;
            int rr = rm / IT, cc = rm - rr * IT;
            int ih = iy0 - 1 + rr, iw = ix0 - 1 + cc;
            float v = 0.f;
            if ((unsigned)ih < (unsigned)Hin && (unsigned)iw < (unsigned)Win)
                v = in[((long)b * Cin + ci0 + c) * inHW + (long)ih * Win + iw];
            if (IN_RELU) v = fmaxf(v, 0.f);
            tile[c * CSZ + rr * RS + cc] = v;
        }
        __syncthreads();
        #pragma unroll
        for (int c = 0; c < NCI; c++) {
            const float* tp = tile + c * CSZ + tiy * RS + tix;
            float n00 = tp[0],        n01 = tp[1],          n02 = tp[2];
            float n10 = tp[RS],       n11 = tp[RS + 1],     n12 = tp[RS + 2];
            float n20 = tp[2 * RS],   n21 = tp[2 * RS + 1], n22 = tp[2 * RS + 2];
            const float* wb = w + ((long)(ci0 + c) * Cout + co0) * 16;
            #pragma unroll
            for (int cq = 0; cq < CQ; cq++) {
                const float* wk = wb + cq * 16;
                float a0 = acc[cq][0], a1 = acc[cq][1];
                float a2 = acc[cq][2], a3 = acc[cq][3];
                a0 = fmaf(n11, wk[5],  fmaf(n10, wk[7],  a0));
                a0 = fmaf(n01, wk[13], fmaf(n00, wk[15], a0));
                a1 = fmaf(n12, wk[4],  fmaf(n11, wk[6],  a1));
                a1 = fmaf(n02, wk[12], fmaf(n01, wk[14], a1));
                a2 = fmaf(n21, wk[1],  fmaf(n20, wk[3],  a2));
                a2 = fmaf(n11, wk[9],  fmaf(n10, wk[11], a2));
                a3 = fmaf(n22, wk[0],  fmaf(n21, wk[2],  a3));
                a3 = fmaf(n12, wk[8],  fmaf(n11, wk[10], a3));
                acc[cq][0] = a0; acc[cq][1] = a1;
                acc[cq][2] = a2; acc[cq][3] = a3;
            }
        }
    }

    int oh0 = (iy0 + tiy) << 1;
    int ow0 = (ix0 + tix) << 1;
    long ostride = (long)Hout * Wout;
    long obase = (((long)b * Cout + co0) * Hout + oh0) * Wout + ow0;
    #pragma unroll
    for (int c = 0; c < CQ; c++) {
        #pragma unroll
        for (int j = 0; j < 4; j++) {
            float v = acc[c][j];
            if (OUT_RELU) v = fmaxf(v, 0.f);
            if (OUT_TANH) v = tanhf(v);
            out[obase + c * ostride + (j >> 1) * (long)Wout + (j & 1)] = v;
        }
    }
}

// numpy pairwise sum-of-squares over 64 fp32 values.
__device__ __forceinline__ float np_sumsq64(const float* v) {
    float r[8];
    #pragma unroll
    for (int j = 0; j < 8; j++) r[j] = __fmul_rn(v[j], v[j]);
    #pragma unroll
    for (int i = 8; i < 64; i += 8) {
        #pragma unroll
        for (int j = 0; j < 8; j++)
            r[j] = __fadd_rn(r[j], __fmul_rn(v[i + j], v[i + j]));
    }
    float s01 = __fadd_rn(r[0], r[1]), s23 = __fadd_rn(r[2], r[3]);
    float s45 = __fadd_rn(r[4], r[5]), s67 = __fadd_rn(r[6], r[7]);
    return __fadd_rn(__fadd_rn(s01, s23), __fadd_rn(s45, s67));
}

__global__ void codenorm_kernel(const float* __restrict__ cb, float* __restrict__ cn)
{
    int k = blockIdx.x * 64 + threadIdx.x;
    if (k >= 512) return;
    float row[64];
    #pragma unroll
    for (int d = 0; d < 64; d++) row[d] = cb[k * 64 + d];
    cn[k] = np_sumsq64(row);
}

// VQ: np-exact fp32 chain; st = fl(z + fl(q-z)).
// 64 px/block; 4 threads/px scan disjoint ascending k-quarters (each quarter's
// fmaf chain identical to the full scan's), merged in quarter order with
// strict < — equivalent to the single ascending strict-< scan (lowest-k ties).
__global__ __launch_bounds__(256)
void vq_kernel(const float* __restrict__ z, const float* __restrict__ cb,
               const float* __restrict__ cn, float* __restrict__ st,
               double* __restrict__ loss_sum, int B)
{
    __shared__ float zt[64][64];
    __shared__ float bd[3][64];
    __shared__ int   bk[3][64];
    int t = threadIdx.x;
    long pg = (long)blockIdx.x * 64;
    int b  = (int)(pg >> 12);
    int p0 = (int)(pg & 4095);
    const float* zb = z + (long)b * 64 * 4096 + p0;
    for (int e = t; e < 64 * 64; e += 256) {
        int d = e >> 6, px = e & 63;
        zt[d][px] = zb[(long)d * 4096 + px];
    }
    __syncthreads();

    int px = t & 63;
    int h  = t >> 6;                 // k-quarter index = wave index
    float zr[64];
    #pragma unroll
    for (int d = 0; d < 64; d++) zr[d] = zt[d][px];

    float s1 = np_sumsq64(zr);

    float best = INFINITY;
    int bi = 0;
    int k0 = h << 7;
    for (int k = k0; k < k0 + 128; k += 4) {
        const float* c0 = cb + (k + 0) * 64;
        const float* c1 = cb + (k + 1) * 64;
        const float* c2 = cb + (k + 2) * 64;
        const float* c3 = cb + (k + 3) * 64;
        float m0 = 0.f, m1 = 0.f, m2 = 0.f, m3 = 0.f;
        #pragma unroll
        for (int d = 0; d < 64; d++) {
            float zd = zr[d];
            m0 = fmaf(zd, c0[d], m0);
            m1 = fmaf(zd, c1[d], m1);
            m2 = fmaf(zd, c2[d], m2);
            m3 = fmaf(zd, c3[d], m3);
        }
        float d0 = __fadd_rn(__fsub_rn(s1, __fmul_rn(2.f, m0)), cn[k + 0]);
        float d1 = __fadd_rn(__fsub_rn(s1, __fmul_rn(2.f, m1)), cn[k + 1]);
        float d2 = __fadd_rn(__fsub_rn(s1, __fmul_rn(2.f, m2)), cn[k + 2]);
        float d3 = __fadd_rn(__fsub_rn(s1, __fmul_rn(2.f, m3)), cn[k + 3]);
        if (d0 < best) { best = d0; bi = k + 0; }
        if (d1 < best) { best = d1; bi = k + 1; }
        if (d2 < best) { best = d2; bi = k + 2; }
        if (d3 < best) { best = d3; bi = k + 3; }
    }

    if (h) { bd[h - 1][px] = best; bk[h - 1][px] = bi; }
    __syncthreads();
    if (h == 0) {
        #pragma unroll
        for (int j = 0; j < 3; j++) {
            float dj = bd[j][px];
            if (dj < best) { best = dj; bi = bk[j][px]; }
        }
        const float* cbest = cb + bi * 64;
        float* sp = st + (long)b * 64 * 4096 + (p0 + px);
        double ls = 0.0;
        #pragma unroll
        for (int d = 0; d < 64; d++) {
            float qv = cbest[d];
            float zv = zr[d];
            float diff = __fsub_rn(qv, zv);
            double dd = (double)qv - (double)zv;
            ls += dd * dd;
            sp[(long)d * 4096] = __fadd_rn(zv, diff);
        }
        #pragma unroll
        for (int off = 32; off > 0; off >>= 1) ls += __shfl_down(ls, off, 64);
        if (px == 0) atomicAdd(loss_sum, ls);
    }
}

__global__ void loss_final_kernel(const double* __restrict__ s, float* __restrict__ out)
{
    out[0] = (float)(1.25 * s[0] / 8388608.0);   // fp32 loss store
}

extern "C" void kernel_launch(void* const* d_in, const int* in_sizes, int n_in,
                              void* d_out, int out_size, void* d_ws, size_t ws_size,
                              hipStream_t stream)
{
    const float* x        = (const float*)d_in[0];
    const float* enc_w1   = (const float*)d_in[1];
    const float* enc_b1   = (const float*)d_in[2];
    const float* enc_w2   = (const float*)d_in[3];
    const float* enc_b2   = (const float*)d_in[4];
    const float* enc_w3   = (const float*)d_in[5];
    const float* enc_b3   = (const float*)d_in[6];
    const float* enc_rw1  = (const float*)d_in[7];
    const float* enc_rb1  = (const float*)d_in[8];
    const float* enc_rw2  = (const float*)d_in[9];
    const float* enc_rb2  = (const float*)d_in[10];
    const float* pvq_w    = (const float*)d_in[11];
    const float* pvq_b    = (const float*)d_in[12];
    const float* codebook = (const float*)d_in[13];
    const float* dec_w1   = (const float*)d_in[14];
    const float* dec_b1   = (const float*)d_in[15];
    const float* dec_rw1  = (const float*)d_in[16];
    const float* dec_rb1  = (const float*)d_in[17];
    const float* dec_rw2  = (const float*)d_in[18];
    const float* dec_rb2  = (const float*)d_in[19];
    const float* dt1_w    = (const float*)d_in[20];
    const float* dt1_b    = (const float*)d_in[21];
    const float* dt2_w    = (const float*)d_in[22];
    const float* dt2_b    = (const float*)d_in[23];

    float* out = (float*)d_out;            // fp32 output buffer (ref dtype)
    char* wsb = (char*)d_ws;

    float*  CN = (float*)wsb;              // 512 floats
    double* LS = (double*)(wsb + 4096);    // 1 double
    const size_t SMALLB = 4352;

    // Aliased layout, 12 MB/sample:
    //  P region (8MB/s): A64 (enc1 out, dead after enc2) -> C64(4MB) T64(1MB)
    //                    Z32(1MB) Qf(1MB); Ef(4MB, after C64/T64/Z32 dead)
    //  Q region (4MB/s): B64 (enc2 out, dead after enc3) -> Df(2MB) Tf(0.5MB)
    const size_t perSampleB = 12582912;    // 8MB + 4MB

    int Bc = 32;
    while (Bc > 1 && SMALLB + perSampleB * Bc + 1024 > ws_size) Bc >>= 1;
    const int nChunks = 32 / Bc;

    char* base  = wsb + SMALLB;
    char* qbase = base + (size_t)Bc * 8388608;
    double* A64 = (double*)base;                              // Bc x 1048576 d
    double* C64 = (double*)base;                              // Bc x 524288 d
    double* T64 = (double*)(base + (size_t)Bc * 4194304);     // Bc x 131072 d
    float*  Z32 = (float*)(base + (size_t)Bc * 5242880);      // Bc x 262144 f
    float*  Qf  = (float*)(base + (size_t)Bc * 6291456);      // Bc x 262144 f
    float*  Ef  = (float*)base;                               // Bc x 1048576 f
    double* B64 = (double*)qbase;                             // Bc x 524288 d
    float*  Df  = (float*)qbase;                              // Bc x 524288 f
    float*  Tf  = (float*)(qbase + (size_t)Bc * 2097152);     // Bc x 131072 f

    hipMemsetAsync(LS, 0, sizeof(double), stream);
    codenorm_kernel<<<8, 64, 0, stream>>>(codebook, CN);

    for (int c = 0; c < nChunks; c++) {
        const float* xc = x + (long)c * Bc * 3 * 65536;
        float* outc = out + (long)c * Bc * 3 * 65536;

        // ---- encoder (fp64 accumulate -> fp32 z) ----
        // enc1: 4x4 s2 3->64, 256->128, OUT_RELU. grid 2048.
        conv_tiled<float,double,double,4,2,1,false,true,false,3,32>
            <<<Bc*8*8*2, 256, 0, stream>>>(
            xc, enc_w1, enc_b1, nullptr, A64, Bc, 3, 256, 256, 64, 128, 128);
        // enc2: 4x4 s2 64->128, 128->64, OUT_RELU. COB=16: grid 2048, 8 blk/CU.
        conv_tiled<double,double,double,4,2,1,false,true,false,2,16>
            <<<Bc*4*4*8, 256, 0, stream>>>(
            A64, enc_w2, enc_b2, nullptr, B64, Bc, 64, 128, 128, 128, 64, 64);
        // enc3: 3x3 s1 128->128. COB=16: grid 2048.
        conv_tiled<double,double,double,3,1,1,false,false,false,4,16>
            <<<Bc*4*4*8, 256, 0, stream>>>(
            B64, enc_w3, enc_b3, nullptr, C64, Bc, 128, 64, 64, 128, 64, 64);
        for (int i = 0; i < 2; i++) {
            // res1: 3x3 128->32, IN_RELU. COB=8: grid 1024.
            conv_tiled<double,double,double,3,1,1,true,false,false,8,8>
                <<<Bc*4*4*4, 256, 0, stream>>>(
                C64, enc_rw1 + (long)i*32*128*9, enc_rb1 + i*32, nullptr, T64,
                Bc, 128, 64, 64, 32, 64, 64);
            // res2: 1x1 32->128, IN_RELU, +residual C64, in-place. COB=16: grid 2048.
            conv_tiled<double,double,double,1,1,0,true,false,true,8,16>
                <<<Bc*4*4*8, 256, 0, stream>>>(
                T64, enc_rw2 + (long)i*128*32, enc_rb2 + i*128, C64, C64,
                Bc, 32, 64, 64, 128, 64, 64);
        }
        // pvq: 1x1 128->64, IN_RELU, fp32 store. COB=16: grid 1024.
        conv_tiled<double,double,float,1,1,0,true,false,false,8,16>
            <<<Bc*4*4*4, 256, 0, stream>>>(
            C64, pvq_w, pvq_b, nullptr, Z32, Bc, 128, 64, 64, 64, 64, 64);

        // ---- VQ (np-exact fp32), 64 px/block, 4-way k-split: grid 1024 ----
        vq_kernel<<<Bc * 64, 256, 0, stream>>>(Z32, codebook, CN, Qf, LS, Bc);

        // ---- decoder (fp32), fp32 output stores ----
        // dec1: 3x3 64->128. Reads Qf, writes Df (B64 dead).
        conv_tiled<float,float,float,3,1,1,false,false,false,8,16>
            <<<Bc*4*4*8, 256, 0, stream>>>(
            Qf, dec_w1, dec_b1, nullptr, Df, Bc, 64, 64, 64, 128, 64, 64);
        for (int i = 0; i < 2; i++) {
            conv_tiled<float,float,float,3,1,1,true,false,false,8,8>
                <<<Bc*4*4*4, 256, 0, stream>>>(
                Df, dec_rw1 + (long)i*32*128*9, dec_rb1 + i*32, nullptr, Tf,
                Bc, 128, 64, 64, 32, 64, 64);
            conv_tiled<float,float,float,1,1,0,true,false,true,16,16>
                <<<Bc*4*4*8, 256, 0, stream>>>(
                Tf, dec_rw2 + (long)i*128*32, dec_rb2 + i*128, Df, Df,
                Bc, 32, 64, 64, 128, 64, 64);
        }
        // dt1: deconv 128->64, 64->128, IN_RELU + OUT_RELU. Writes Ef.
        deconv_tiled<8,true,true,false,8><<<Bc*4*4*8, 256, 0, stream>>>(
            Df, dt1_w, dt1_b, Ef, Bc, 128, 64, 64, 64);
        // dt2: deconv 64->3, 128->256, tanh, writes final output.
        deconv_tiled<3,false,false,true,8><<<Bc*8*8*1, 256, 0, stream>>>(
            Ef, dt2_w, dt2_b, outc, Bc, 64, 128, 128, 3);
    }

    loss_final_kernel<<<1, 1, 0, stream>>>(LS, out + 6291456);
}

// Round 9
// 6247.220 us; speedup vs baseline: 12.2979x; 1.0905x over previous
//
#include <hip/hip_runtime.h>
#include <hip/hip_bf16.h>
#include <math.h>

// R24: revert R23's MFMA encoder (FAILED: fp64 sum reorder flipped VQ argmin
// indices -> 3.5e-3; the argmin is a discontinuity, encoder order is
// load-bearing). Base = R22 (passing, 6.81ms). Changes, both value-exact:
//  - deconv_tiled: float4 weight loads (16 consecutive 64B-aligned floats per
//    cq were scalar loads because alignment wasn't provable; dt1 issued ~128
//    scalar weight loads per ci vs 64 fma -> weight-issue bound). Same
//    values, same fmaf chains -> bit-identical.
//  - conv_tiled fp32 tiles: RS rounded to mult-of-4 (20) + __align__(16) so
//    iv[] reads merge into ds_read_b128/b64 (18 scalar -> 6 vector per ci).
//    fp64 tiles keep RS=IT+1 (verified layout).
// Pipeline: fp64 encoder -> fp32 z, np-exact fp32 VQ, straight-through
// fl(z+fl(q-z)), fp32 decoder, fp32 output writes.

template<typename T> __device__ __forceinline__ T fmaT(T a, T b, T c);
template<> __device__ __forceinline__ double fmaT(double a, double b, double c) { return fma(a, b, c); }
template<> __device__ __forceinline__ float  fmaT(float a, float b, float c)    { return fmaf(a, b, c); }
template<typename T> __device__ __forceinline__ T maxT(T a, T b);
template<> __device__ __forceinline__ double maxT(double a, double b) { return fmax(a, b); }
template<> __device__ __forceinline__ float  maxT(float a, float b)   { return fmaxf(a, b); }

// ---------------------------------------------------------------------------
// LDS-tiled conv. 256 threads = 4 waves; 16x16 output tile x COB couts.
// Single-buffer stage -> barrier -> compute. fp64: RS=IT+1 (odd, bank
// spread). fp32: RS=mult-of-4 so compute reads vectorize to b128/b64.
// Accumulation per output: ci asc, kh asc, kw asc — bit-identical to direct.
// ---------------------------------------------------------------------------
template<typename TIn, typename TAcc, typename TOut, int K, int S, int PAD,
         bool IN_RELU, bool OUT_RELU, bool RES_ADD, int NCI, int COB>
__global__ __launch_bounds__(256, 3)
void conv_tiled(const TIn* __restrict__ in, const float* __restrict__ w,
                const float* __restrict__ bias, const TAcc* __restrict__ res,
                TOut* __restrict__ out,
                int B, int Cin, int Hin, int Win, int Cout, int Hout, int Wout)
{
    constexpr int TILE = 16;
    constexpr int IT   = (TILE - 1) * S + K;   // input tile edge incl. halo
    constexpr int RS   = (sizeof(TAcc) == 8) ? (IT + 1) : ((IT + 4) & ~3);
    constexpr int ITT  = IT * IT;
    constexpr int CSZ  = IT * RS;
    constexpr int NEL  = NCI * ITT;
    constexpr int CPW  = COB / 4;
    constexpr int PIX  = 4;
    constexpr int WIN  = (PIX - 1) * S + K;

    __shared__ __align__(16) TAcc tile[NCI * CSZ];

    int ntx = Wout / TILE, nty = Hout / TILE, ncb = Cout / COB;
    int g = blockIdx.x;
    int tx = g % ntx; g /= ntx;
    int ty = g % nty; g /= nty;
    int cb = g % ncb;
    int b  = g / ncb;

    int t    = threadIdx.x;
    int wave = t >> 6;
    int lowg = t & 3;
    int loh  = (t >> 2) & 15;
    int co0  = cb * COB + wave * CPW;
    int oh0t = ty * TILE, ow0t = tx * TILE;
    int oh   = oh0t + loh;
    int ow0  = ow0t + lowg * PIX;

    TAcc acc[CPW][PIX];
    #pragma unroll
    for (int c = 0; c < CPW; c++) {
        TAcc bv = (TAcc)bias[co0 + c];
        #pragma unroll
        for (int j = 0; j < PIX; j++) acc[c][j] = bv;
    }

    const int ihb = oh0t * S - PAD;
    const int iwb = ow0t * S - PAD;
    const long inHW = (long)Hin * Win;
    const int KK  = K * K;
    const int wCK = Cin * KK;

    for (int ci0 = 0; ci0 < Cin; ci0 += NCI) {
        __syncthreads();
        for (int e = t; e < NEL; e += 256) {
            int c = e / ITT, rm = e - c * ITT;
            int rr = rm / IT, cc = rm - rr * IT;
            int ih = ihb + rr, iw = iwb + cc;
            TAcc v = (TAcc)0;
            if ((unsigned)ih < (unsigned)Hin && (unsigned)iw < (unsigned)Win)
                v = (TAcc)in[((long)b * Cin + ci0 + c) * inHW + (long)ih * Win + iw];
            if (IN_RELU) v = maxT(v, (TAcc)0);
            tile[c * CSZ + rr * RS + cc] = v;
        }
        __syncthreads();
        #pragma unroll
        for (int c = 0; c < NCI; c++) {
            const float* wp = w + ((long)co0 * Cin + (ci0 + c)) * KK;
            #pragma unroll
            for (int kh = 0; kh < K; kh++) {
                const TAcc* rp = tile + c * CSZ + (loh * S + kh) * RS + lowg * PIX * S;
                TAcc iv[WIN];
                #pragma unroll
                for (int x = 0; x < WIN; x++) iv[x] = rp[x];
                #pragma unroll
                for (int c2 = 0; c2 < CPW; c2++) {
                    #pragma unroll
                    for (int kw = 0; kw < K; kw++) {
                        TAcc wv = (TAcc)wp[c2 * wCK + kh * K + kw];
                        #pragma unroll
                        for (int j = 0; j < PIX; j++)
                            acc[c2][j] = fmaT(iv[j * S + kw], wv, acc[c2][j]);
                    }
                }
            }
        }
    }

    long ostride = (long)Hout * Wout;
    long obase = (((long)b * Cout + co0) * Hout + oh) * Wout + ow0;
    #pragma unroll
    for (int c = 0; c < CPW; c++) {
        #pragma unroll
        for (int j = 0; j < PIX; j++) {
            TAcc v = acc[c][j];
            if (RES_ADD) v += res[obase + c * ostride + j];
            if (OUT_RELU) v = maxT(v, (TAcc)0);
            out[obase + c * ostride + j] = (TOut)v;
        }
    }
}

// ---------------------------------------------------------------------------
// LDS-tiled ConvTranspose2d k=4 s=2 p=1, fp32, 4-wave blocks, padded rows.
// Each thread owns input pos (tiy,tix) of a 16x16 tile (18x18 halo in LDS)
// and computes its 2x2 output quad for CQ couts. Weights loaded as float4
// (w quad rows: wA=w[0..3], wB=w[4..7], wC=w[8..11], wD=w[12..15]).
// Per-output fmaf chains replicate the original deconv exactly:
//   even oh: kh=1 (row iy) then kh=3 (row iy-1); odd oh: kh=0 (iy+1), kh=2 (iy)
//   even ow: +i[iw-1]*w[kh][3] then +i[iw]*w[kh][1]
//   odd  ow: +i[iw]*w[kh][2]  then +i[iw+1]*w[kh][0]
// ---------------------------------------------------------------------------
template<int CQ, bool IN_RELU, bool OUT_RELU, bool OUT_TANH, int NCI>
__global__ __launch_bounds__(256, 3)
void deconv_tiled(const float* __restrict__ in, const float* __restrict__ w,
                  const float* __restrict__ bias, float* __restrict__ out,
                  int B, int Cin, int Hin, int Win, int Cout)
{
    constexpr int IT  = 18;
    constexpr int ITT = IT * IT;
    constexpr int RS  = IT + 1;
    constexpr int CSZ = IT * RS;
    constexpr int NEL = NCI * ITT;
    int Hout = Hin << 1, Wout = Win << 1;

    __shared__ __align__(16) float tile[NCI * CSZ];

    int ntx = Win >> 4, nty = Hin >> 4, ncb = Cout / CQ;
    int g = blockIdx.x;
    int tx = g % ntx; g /= ntx;
    int ty = g % nty; g /= nty;
    int cb = g % ncb;
    int b  = g / ncb;

    int t   = threadIdx.x;
    int tix = t & 15;
    int tiy = t >> 4;
    int ix0 = tx << 4, iy0 = ty << 4;
    int co0 = cb * CQ;

    float acc[CQ][4];
    #pragma unroll
    for (int c = 0; c < CQ; c++) {
        float bv = bias[co0 + c];
        #pragma unroll
        for (int j = 0; j < 4; j++) acc[c][j] = bv;
    }

    const long inHW = (long)Hin * Win;

    for (int ci0 = 0; ci0 < Cin; ci0 += NCI) {
        __syncthreads();
        for (int e = t; e < NEL; e += 256) {
            int c = e / ITT, rm = e - c * ITT;
            int rr = rm / IT, cc = rm - rr * IT;
            int ih = iy0 - 1 + rr, iw = ix0 - 1 + cc;
            float v = 0.f;
            if ((unsigned)ih < (unsigned)Hin && (unsigned)iw < (unsigned)Win)
                v = in[((long)b * Cin + ci0 + c) * inHW + (long)ih * Win + iw];
            if (IN_RELU) v = fmaxf(v, 0.f);
            tile[c * CSZ + rr * RS + cc] = v;
        }
        __syncthreads();
        #pragma unroll
        for (int c = 0; c < NCI; c++) {
            const float* tp = tile + c * CSZ + tiy * RS + tix;
            float n00 = tp[0],        n01 = tp[1],          n02 = tp[2];
            float n10 = tp[RS],       n11 = tp[RS + 1],     n12 = tp[RS + 2];
            float n20 = tp[2 * RS],   n21 = tp[2 * RS + 1], n22 = tp[2 * RS + 2];
            const float4* wb4 = reinterpret_cast<const float4*>(
                w + ((long)(ci0 + c) * Cout + co0) * 16);
            #pragma unroll
            for (int cq = 0; cq < CQ; cq++) {
                float4 wA = wb4[cq * 4 + 0];   // w[kh=0][0..3]
                float4 wB = wb4[cq * 4 + 1];   // w[kh=1][0..3]
                float4 wC = wb4[cq * 4 + 2];   // w[kh=2][0..3]
                float4 wD = wb4[cq * 4 + 3];   // w[kh=3][0..3]
                float a0 = acc[cq][0], a1 = acc[cq][1];
                float a2 = acc[cq][2], a3 = acc[cq][3];
                a0 = fmaf(n11, wB.y, fmaf(n10, wB.w, a0));   // wk[5], wk[7]
                a0 = fmaf(n01, wD.y, fmaf(n00, wD.w, a0));   // wk[13], wk[15]
                a1 = fmaf(n12, wB.x, fmaf(n11, wB.z, a1));   // wk[4], wk[6]
                a1 = fmaf(n02, wD.x, fmaf(n01, wD.z, a1));   // wk[12], wk[14]
                a2 = fmaf(n21, wA.y, fmaf(n20, wA.w, a2));   // wk[1], wk[3]
                a2 = fmaf(n11, wC.y, fmaf(n10, wC.w, a2));   // wk[9], wk[11]
                a3 = fmaf(n22, wA.x, fmaf(n21, wA.z, a3));   // wk[0], wk[2]
                a3 = fmaf(n12, wC.x, fmaf(n11, wC.z, a3));   // wk[8], wk[10]
                acc[cq][0] = a0; acc[cq][1] = a1;
                acc[cq][2] = a2; acc[cq][3] = a3;
            }
        }
    }

    int oh0 = (iy0 + tiy) << 1;
    int ow0 = (ix0 + tix) << 1;
    long ostride = (long)Hout * Wout;
    long obase = (((long)b * Cout + co0) * Hout + oh0) * Wout + ow0;
    #pragma unroll
    for (int c = 0; c < CQ; c++) {
        #pragma unroll
        for (int j = 0; j < 4; j++) {
            float v = acc[c][j];
            if (OUT_RELU) v = fmaxf(v, 0.f);
            if (OUT_TANH) v = tanhf(v);
            out[obase + c * ostride + (j >> 1) * (long)Wout + (j & 1)] = v;
        }
    }
}

// numpy pairwise sum-of-squares over 64 fp32 values.
__device__ __forceinline__ float np_sumsq64(const float* v) {
    float r[8];
    #pragma unroll
    for (int j = 0; j < 8; j++) r[j] = __fmul_rn(v[j], v[j]);
    #pragma unroll
    for (int i = 8; i < 64; i += 8) {
        #pragma unroll
        for (int j = 0; j < 8; j++)
            r[j] = __fadd_rn(r[j], __fmul_rn(v[i + j], v[i + j]));
    }
    float s01 = __fadd_rn(r[0], r[1]), s23 = __fadd_rn(r[2], r[3]);
    float s45 = __fadd_rn(r[4], r[5]), s67 = __fadd_rn(r[6], r[7]);
    return __fadd_rn(__fadd_rn(s01, s23), __fadd_rn(s45, s67));
}

__global__ void codenorm_kernel(const float* __restrict__ cb, float* __restrict__ cn)
{
    int k = blockIdx.x * 64 + threadIdx.x;
    if (k >= 512) return;
    float row[64];
    #pragma unroll
    for (int d = 0; d < 64; d++) row[d] = cb[k * 64 + d];
    cn[k] = np_sumsq64(row);
}

// VQ: np-exact fp32 chain; st = fl(z + fl(q-z)). As R22 (passing).
__global__ __launch_bounds__(256)
void vq_kernel(const float* __restrict__ z, const float* __restrict__ cb,
               const float* __restrict__ cn, float* __restrict__ st,
               double* __restrict__ loss_sum, int B)
{
    __shared__ float zt[64][64];
    __shared__ float bd[3][64];
    __shared__ int   bk[3][64];
    int t = threadIdx.x;
    long pg = (long)blockIdx.x * 64;
    int b  = (int)(pg >> 12);
    int p0 = (int)(pg & 4095);
    const float* zb = z + (long)b * 64 * 4096 + p0;
    for (int e = t; e < 64 * 64; e += 256) {
        int d = e >> 6, px = e & 63;
        zt[d][px] = zb[(long)d * 4096 + px];
    }
    __syncthreads();

    int px = t & 63;
    int h  = t >> 6;
    float zr[64];
    #pragma unroll
    for (int d = 0; d < 64; d++) zr[d] = zt[d][px];

    float s1 = np_sumsq64(zr);

    float best = INFINITY;
    int bi = 0;
    int k0 = h << 7;
    for (int k = k0; k < k0 + 128; k += 4) {
        const float* c0 = cb + (k + 0) * 64;
        const float* c1 = cb + (k + 1) * 64;
        const float* c2 = cb + (k + 2) * 64;
        const float* c3 = cb + (k + 3) * 64;
        float m0 = 0.f, m1 = 0.f, m2 = 0.f, m3 = 0.f;
        #pragma unroll
        for (int d = 0; d < 64; d++) {
            float zd = zr[d];
            m0 = fmaf(zd, c0[d], m0);
            m1 = fmaf(zd, c1[d], m1);
            m2 = fmaf(zd, c2[d], m2);
            m3 = fmaf(zd, c3[d], m3);
        }
        float d0 = __fadd_rn(__fsub_rn(s1, __fmul_rn(2.f, m0)), cn[k + 0]);
        float d1 = __fadd_rn(__fsub_rn(s1, __fmul_rn(2.f, m1)), cn[k + 1]);
        float d2 = __fadd_rn(__fsub_rn(s1, __fmul_rn(2.f, m2)), cn[k + 2]);
        float d3 = __fadd_rn(__fsub_rn(s1, __fmul_rn(2.f, m3)), cn[k + 3]);
        if (d0 < best) { best = d0; bi = k + 0; }
        if (d1 < best) { best = d1; bi = k + 1; }
        if (d2 < best) { best = d2; bi = k + 2; }
        if (d3 < best) { best = d3; bi = k + 3; }
    }

    if (h) { bd[h - 1][px] = best; bk[h - 1][px] = bi; }
    __syncthreads();
    if (h == 0) {
        #pragma unroll
        for (int j = 0; j < 3; j++) {
            float dj = bd[j][px];
            if (dj < best) { best = dj; bi = bk[j][px]; }
        }
        const float* cbest = cb + bi * 64;
        float* sp = st + (long)b * 64 * 4096 + (p0 + px);
        double ls = 0.0;
        #pragma unroll
        for (int d = 0; d < 64; d++) {
            float qv = cbest[d];
            float zv = zr[d];
            float diff = __fsub_rn(qv, zv);
            double dd = (double)qv - (double)zv;
            ls += dd * dd;
            sp[(long)d * 4096] = __fadd_rn(zv, diff);
        }
        #pragma unroll
        for (int off = 32; off > 0; off >>= 1) ls += __shfl_down(ls, off, 64);
        if (px == 0) atomicAdd(loss_sum, ls);
    }
}

__global__ void loss_final_kernel(const double* __restrict__ s, float* __restrict__ out)
{
    out[0] = (float)(1.25 * s[0] / 8388608.0);   // fp32 loss store
}

extern "C" void kernel_launch(void* const* d_in, const int* in_sizes, int n_in,
                              void* d_out, int out_size, void* d_ws, size_t ws_size,
                              hipStream_t stream)
{
    const float* x        = (const float*)d_in[0];
    const float* enc_w1   = (const float*)d_in[1];
    const float* enc_b1   = (const float*)d_in[2];
    const float* enc_w2   = (const float*)d_in[3];
    const float* enc_b2   = (const float*)d_in[4];
    const float* enc_w3   = (const float*)d_in[5];
    const float* enc_b3   = (const float*)d_in[6];
    const float* enc_rw1  = (const float*)d_in[7];
    const float* enc_rb1  = (const float*)d_in[8];
    const float* enc_rw2  = (const float*)d_in[9];
    const float* enc_rb2  = (const float*)d_in[10];
    const float* pvq_w    = (const float*)d_in[11];
    const float* pvq_b    = (const float*)d_in[12];
    const float* codebook = (const float*)d_in[13];
    const float* dec_w1   = (const float*)d_in[14];
    const float* dec_b1   = (const float*)d_in[15];
    const float* dec_rw1  = (const float*)d_in[16];
    const float* dec_rb1  = (const float*)d_in[17];
    const float* dec_rw2  = (const float*)d_in[18];
    const float* dec_rb2  = (const float*)d_in[19];
    const float* dt1_w    = (const float*)d_in[20];
    const float* dt1_b    = (const float*)d_in[21];
    const float* dt2_w    = (const float*)d_in[22];
    const float* dt2_b    = (const float*)d_in[23];

    float* out = (float*)d_out;            // fp32 output buffer (ref dtype)
    char* wsb = (char*)d_ws;

    float*  CN = (float*)wsb;              // 512 floats
    double* LS = (double*)(wsb + 4096);    // 1 double
    const size_t SMALLB = 4352;

    // Aliased layout, 12 MB/sample (as R21/R22).
    const size_t perSampleB = 12582912;

    int Bc = 32;
    while (Bc > 1 && SMALLB + perSampleB * Bc + 1024 > ws_size) Bc >>= 1;
    const int nChunks = 32 / Bc;

    char* base  = wsb + SMALLB;
    char* qbase = base + (size_t)Bc * 8388608;
    double* A64 = (double*)base;                              // Bc x 1048576 d
    double* C64 = (double*)base;                              // Bc x 524288 d
    double* T64 = (double*)(base + (size_t)Bc * 4194304);     // Bc x 131072 d
    float*  Z32 = (float*)(base + (size_t)Bc * 5242880);      // Bc x 262144 f
    float*  Qf  = (float*)(base + (size_t)Bc * 6291456);      // Bc x 262144 f
    float*  Ef  = (float*)base;                               // Bc x 1048576 f
    double* B64 = (double*)qbase;                             // Bc x 524288 d
    float*  Df  = (float*)qbase;                              // Bc x 524288 f
    float*  Tf  = (float*)(qbase + (size_t)Bc * 2097152);     // Bc x 131072 f

    hipMemsetAsync(LS, 0, sizeof(double), stream);
    codenorm_kernel<<<8, 64, 0, stream>>>(codebook, CN);

    for (int c = 0; c < nChunks; c++) {
        const float* xc = x + (long)c * Bc * 3 * 65536;
        float* outc = out + (long)c * Bc * 3 * 65536;

        // ---- encoder (fp64 accumulate -> fp32 z), as R22 ----
        conv_tiled<float,double,double,4,2,1,false,true,false,3,32>
            <<<Bc*8*8*2, 256, 0, stream>>>(
            xc, enc_w1, enc_b1, nullptr, A64, Bc, 3, 256, 256, 64, 128, 128);
        conv_tiled<double,double,double,4,2,1,false,true,false,2,16>
            <<<Bc*4*4*8, 256, 0, stream>>>(
            A64, enc_w2, enc_b2, nullptr, B64, Bc, 64, 128, 128, 128, 64, 64);
        conv_tiled<double,double,double,3,1,1,false,false,false,4,16>
            <<<Bc*4*4*8, 256, 0, stream>>>(
            B64, enc_w3, enc_b3, nullptr, C64, Bc, 128, 64, 64, 128, 64, 64);
        for (int i = 0; i < 2; i++) {
            conv_tiled<double,double,double,3,1,1,true,false,false,8,8>
                <<<Bc*4*4*4, 256, 0, stream>>>(
                C64, enc_rw1 + (long)i*32*128*9, enc_rb1 + i*32, nullptr, T64,
                Bc, 128, 64, 64, 32, 64, 64);
            conv_tiled<double,double,double,1,1,0,true,false,true,8,16>
                <<<Bc*4*4*8, 256, 0, stream>>>(
                T64, enc_rw2 + (long)i*128*32, enc_rb2 + i*128, C64, C64,
                Bc, 32, 64, 64, 128, 64, 64);
        }
        conv_tiled<double,double,float,1,1,0,true,false,false,8,16>
            <<<Bc*4*4*4, 256, 0, stream>>>(
            C64, pvq_w, pvq_b, nullptr, Z32, Bc, 128, 64, 64, 64, 64, 64);

        // ---- VQ (np-exact fp32), as R22 ----
        vq_kernel<<<Bc * 64, 256, 0, stream>>>(Z32, codebook, CN, Qf, LS, Bc);

        // ---- decoder (fp32), fp32 output stores ----
        conv_tiled<float,float,float,3,1,1,false,false,false,8,16>
            <<<Bc*4*4*8, 256, 0, stream>>>(
            Qf, dec_w1, dec_b1, nullptr, Df, Bc, 64, 64, 64, 128, 64, 64);
        for (int i = 0; i < 2; i++) {
            conv_tiled<float,float,float,3,1,1,true,false,false,8,8>
                <<<Bc*4*4*4, 256, 0, stream>>>(
                Df, dec_rw1 + (long)i*32*128*9, dec_rb1 + i*32, nullptr, Tf,
                Bc, 128, 64, 64, 32, 64, 64);
            conv_tiled<float,float,float,1,1,0,true,false,true,16,16>
                <<<Bc*4*4*8, 256, 0, stream>>>(
                Tf, dec_rw2 + (long)i*128*32, dec_rb2 + i*128, Df, Df,
                Bc, 32, 64, 64, 128, 64, 64);
        }
        // dt1: deconv 128->64, 64->128, IN_RELU + OUT_RELU. float4 weights.
        deconv_tiled<8,true,true,false,8><<<Bc*4*4*8, 256, 0, stream>>>(
            Df, dt1_w, dt1_b, Ef, Bc, 128, 64, 64, 64);
        // dt2: deconv 64->3, 128->256, tanh, writes final output.
        deconv_tiled<3,false,false,true,8><<<Bc*8*8*1, 256, 0, stream>>>(
            Ef, dt2_w, dt2_b, outc, Bc, 64, 128, 128, 3);
    }

    loss_final_kernel<<<1, 1, 0, stream>>>(LS, out + 6291456);
}

// Round 10
// 5959.988 us; speedup vs baseline: 12.8905x; 1.0482x over previous
//
#include <hip/hip_runtime.h>
#include <hip/hip_bf16.h>
#include <math.h>

// R25: LDS weight staging with pre-conversion. Numerics BIT-IDENTICAL to R24.
// R24 counters: enc2 at 69% of its fp64 quarter-rate issue floor. Diagnosis:
// (1) per-use v_cvt_f64_f32 on every weight read (~20-25% extra VALU on the
// critical pipe); (2) 64-lane redundant broadcast weight loads from global
// (weight set/CU > L1 -> L2 latency feeding FMAs).
// Fix: per-round cooperative staging of NCI x COB x K^2 weights into LDS,
// converted to TAcc ONCE at stage time (double(float) exact); compute reads
// are same-address LDS broadcasts. Same for deconv (float4 from LDS).
// Every per-output fma/fmaf chain unchanged -> bit-identical.
// Pipeline: fp64 encoder -> fp32 z, np-exact fp32 VQ, straight-through
// fl(z+fl(q-z)), fp32 decoder, fp32 output writes.

template<typename T> __device__ __forceinline__ T fmaT(T a, T b, T c);
template<> __device__ __forceinline__ double fmaT(double a, double b, double c) { return fma(a, b, c); }
template<> __device__ __forceinline__ float  fmaT(float a, float b, float c)    { return fmaf(a, b, c); }
template<typename T> __device__ __forceinline__ T maxT(T a, T b);
template<> __device__ __forceinline__ double maxT(double a, double b) { return fmax(a, b); }
template<> __device__ __forceinline__ float  maxT(float a, float b)   { return fmaxf(a, b); }

// ---------------------------------------------------------------------------
// LDS-tiled conv. 256 threads = 4 waves; 16x16 output tile x COB couts.
// Single-buffer stage (input tile + weights) -> barrier -> compute.
// fp64 tiles: RS=IT+1. fp32 tiles: RS mult-of-4 (vector ds reads).
// Weights staged to LDS as TAcc (cvt once); compute reads broadcast.
// Accumulation per output: ci asc, kh asc, kw asc — bit-identical to direct.
// ---------------------------------------------------------------------------
template<typename TIn, typename TAcc, typename TOut, int K, int S, int PAD,
         bool IN_RELU, bool OUT_RELU, bool RES_ADD, int NCI, int COB>
__global__ __launch_bounds__(256, 3)
void conv_tiled(const TIn* __restrict__ in, const float* __restrict__ w,
                const float* __restrict__ bias, const TAcc* __restrict__ res,
                TOut* __restrict__ out,
                int B, int Cin, int Hin, int Win, int Cout, int Hout, int Wout)
{
    constexpr int TILE = 16;
    constexpr int IT   = (TILE - 1) * S + K;   // input tile edge incl. halo
    constexpr int RS   = (sizeof(TAcc) == 8) ? (IT + 1) : ((IT + 4) & ~3);
    constexpr int ITT  = IT * IT;
    constexpr int CSZ  = IT * RS;
    constexpr int NEL  = NCI * ITT;
    constexpr int CPW  = COB / 4;
    constexpr int PIX  = 4;
    constexpr int WIN  = (PIX - 1) * S + K;
    constexpr int KK   = K * K;
    constexpr int NWGT = NCI * COB * KK;       // staged weights per round

    __shared__ __align__(16) TAcc tile[NCI * CSZ];
    __shared__ __align__(16) TAcc wlds[NWGT];

    int ntx = Wout / TILE, nty = Hout / TILE, ncb = Cout / COB;
    int g = blockIdx.x;
    int tx = g % ntx; g /= ntx;
    int ty = g % nty; g /= nty;
    int cb = g % ncb;
    int b  = g / ncb;

    int t    = threadIdx.x;
    int wave = t >> 6;
    int lowg = t & 3;
    int loh  = (t >> 2) & 15;
    int co0  = cb * COB + wave * CPW;
    int oh0t = ty * TILE, ow0t = tx * TILE;
    int oh   = oh0t + loh;
    int ow0  = ow0t + lowg * PIX;

    TAcc acc[CPW][PIX];
    #pragma unroll
    for (int c = 0; c < CPW; c++) {
        TAcc bv = (TAcc)bias[co0 + c];
        #pragma unroll
        for (int j = 0; j < PIX; j++) acc[c][j] = bv;
    }

    const int ihb = oh0t * S - PAD;
    const int iwb = ow0t * S - PAD;
    const long inHW = (long)Hin * Win;

    for (int ci0 = 0; ci0 < Cin; ci0 += NCI) {
        __syncthreads();
        for (int e = t; e < NEL; e += 256) {
            int c = e / ITT, rm = e - c * ITT;
            int rr = rm / IT, cc = rm - rr * IT;
            int ih = ihb + rr, iw = iwb + cc;
            TAcc v = (TAcc)0;
            if ((unsigned)ih < (unsigned)Hin && (unsigned)iw < (unsigned)Win)
                v = (TAcc)in[((long)b * Cin + ci0 + c) * inHW + (long)ih * Win + iw];
            if (IN_RELU) v = maxT(v, (TAcc)0);
            tile[c * CSZ + rr * RS + cc] = v;
        }
        for (int e = t; e < NWGT; e += 256) {
            int c   = e / (COB * KK);
            int rm  = e - c * (COB * KK);
            int col = rm / KK;
            int tap = rm - col * KK;
            wlds[e] = (TAcc)w[((long)(cb * COB + col) * Cin + (ci0 + c)) * KK + tap];
        }
        __syncthreads();
        #pragma unroll
        for (int c = 0; c < NCI; c++) {
            const TAcc* wp = wlds + (c * COB + wave * CPW) * KK;
            #pragma unroll
            for (int kh = 0; kh < K; kh++) {
                const TAcc* rp = tile + c * CSZ + (loh * S + kh) * RS + lowg * PIX * S;
                TAcc iv[WIN];
                #pragma unroll
                for (int x = 0; x < WIN; x++) iv[x] = rp[x];
                #pragma unroll
                for (int c2 = 0; c2 < CPW; c2++) {
                    #pragma unroll
                    for (int kw = 0; kw < K; kw++) {
                        TAcc wv = wp[c2 * KK + kh * K + kw];
                        #pragma unroll
                        for (int j = 0; j < PIX; j++)
                            acc[c2][j] = fmaT(iv[j * S + kw], wv, acc[c2][j]);
                    }
                }
            }
        }
    }

    long ostride = (long)Hout * Wout;
    long obase = (((long)b * Cout + co0) * Hout + oh) * Wout + ow0;
    #pragma unroll
    for (int c = 0; c < CPW; c++) {
        #pragma unroll
        for (int j = 0; j < PIX; j++) {
            TAcc v = acc[c][j];
            if (RES_ADD) v += res[obase + c * ostride + j];
            if (OUT_RELU) v = maxT(v, (TAcc)0);
            out[obase + c * ostride + j] = (TOut)v;
        }
    }
}

// ---------------------------------------------------------------------------
// LDS-tiled ConvTranspose2d k=4 s=2 p=1, fp32, 4-wave blocks, padded rows.
// Weights staged to LDS per round, read as float4 broadcasts.
// Per-output fmaf chains replicate the original deconv exactly:
//   even oh: kh=1 (row iy) then kh=3 (row iy-1); odd oh: kh=0 (iy+1), kh=2 (iy)
//   even ow: +i[iw-1]*w[kh][3] then +i[iw]*w[kh][1]
//   odd  ow: +i[iw]*w[kh][2]  then +i[iw+1]*w[kh][0]
// ---------------------------------------------------------------------------
template<int CQ, bool IN_RELU, bool OUT_RELU, bool OUT_TANH, int NCI>
__global__ __launch_bounds__(256, 3)
void deconv_tiled(const float* __restrict__ in, const float* __restrict__ w,
                  const float* __restrict__ bias, float* __restrict__ out,
                  int B, int Cin, int Hin, int Win, int Cout)
{
    constexpr int IT  = 18;
    constexpr int ITT = IT * IT;
    constexpr int RS  = IT + 1;
    constexpr int CSZ = IT * RS;
    constexpr int NEL = NCI * ITT;
    constexpr int NWGT = NCI * CQ * 16;
    int Hout = Hin << 1, Wout = Win << 1;

    __shared__ __align__(16) float tile[NCI * CSZ];
    __shared__ __align__(16) float wlds[NWGT];

    int ntx = Win >> 4, nty = Hin >> 4, ncb = Cout / CQ;
    int g = blockIdx.x;
    int tx = g % ntx; g /= ntx;
    int ty = g % nty; g /= nty;
    int cb = g % ncb;
    int b  = g / ncb;

    int t   = threadIdx.x;
    int tix = t & 15;
    int tiy = t >> 4;
    int ix0 = tx << 4, iy0 = ty << 4;
    int co0 = cb * CQ;

    float acc[CQ][4];
    #pragma unroll
    for (int c = 0; c < CQ; c++) {
        float bv = bias[co0 + c];
        #pragma unroll
        for (int j = 0; j < 4; j++) acc[c][j] = bv;
    }

    const long inHW = (long)Hin * Win;

    for (int ci0 = 0; ci0 < Cin; ci0 += NCI) {
        __syncthreads();
        for (int e = t; e < NEL; e += 256) {
            int c = e / ITT, rm = e - c * ITT;
            int rr = rm / IT, cc = rm - rr * IT;
            int ih = iy0 - 1 + rr, iw = ix0 - 1 + cc;
            float v = 0.f;
            if ((unsigned)ih < (unsigned)Hin && (unsigned)iw < (unsigned)Win)
                v = in[((long)b * Cin + ci0 + c) * inHW + (long)ih * Win + iw];
            if (IN_RELU) v = fmaxf(v, 0.f);
            tile[c * CSZ + rr * RS + cc] = v;
        }
        for (int e = t; e < NWGT; e += 256) {
            int c   = e >> 7;                 // / (CQ*16) only when CQ=8; generic:
            int cc2 = e - c * (CQ * 16);
            int col = cc2 >> 4;
            int tap = cc2 & 15;
            wlds[e] = w[((long)(ci0 + c) * Cout + cb * CQ + col) * 16 + tap];
        }
        __syncthreads();
        #pragma unroll
        for (int c = 0; c < NCI; c++) {
            const float* tp = tile + c * CSZ + tiy * RS + tix;
            float n00 = tp[0],        n01 = tp[1],          n02 = tp[2];
            float n10 = tp[RS],       n11 = tp[RS + 1],     n12 = tp[RS + 2];
            float n20 = tp[2 * RS],   n21 = tp[2 * RS + 1], n22 = tp[2 * RS + 2];
            const float4* wb4 = reinterpret_cast<const float4*>(wlds) + c * CQ * 4;
            #pragma unroll
            for (int cq = 0; cq < CQ; cq++) {
                float4 wA = wb4[cq * 4 + 0];   // w[kh=0][0..3]
                float4 wB = wb4[cq * 4 + 1];   // w[kh=1][0..3]
                float4 wC = wb4[cq * 4 + 2];   // w[kh=2][0..3]
                float4 wD = wb4[cq * 4 + 3];   // w[kh=3][0..3]
                float a0 = acc[cq][0], a1 = acc[cq][1];
                float a2 = acc[cq][2], a3 = acc[cq][3];
                a0 = fmaf(n11, wB.y, fmaf(n10, wB.w, a0));   // wk[5], wk[7]
                a0 = fmaf(n01, wD.y, fmaf(n00, wD.w, a0));   // wk[13], wk[15]
                a1 = fmaf(n12, wB.x, fmaf(n11, wB.z, a1));   // wk[4], wk[6]
                a1 = fmaf(n02, wD.x, fmaf(n01, wD.z, a1));   // wk[12], wk[14]
                a2 = fmaf(n21, wA.y, fmaf(n20, wA.w, a2));   // wk[1], wk[3]
                a2 = fmaf(n11, wC.y, fmaf(n10, wC.w, a2));   // wk[9], wk[11]
                a3 = fmaf(n22, wA.x, fmaf(n21, wA.z, a3));   // wk[0], wk[2]
                a3 = fmaf(n12, wC.x, fmaf(n11, wC.z, a3));   // wk[8], wk[10]
                acc[cq][0] = a0; acc[cq][1] = a1;
                acc[cq][2] = a2; acc[cq][3] = a3;
            }
        }
    }

    int oh0 = (iy0 + tiy) << 1;
    int ow0 = (ix0 + tix) << 1;
    long ostride = (long)Hout * Wout;
    long obase = (((long)b * Cout + co0) * Hout + oh0) * Wout + ow0;
    #pragma unroll
    for (int c = 0; c < CQ; c++) {
        #pragma unroll
        for (int j = 0; j < 4; j++) {
            float v = acc[c][j];
            if (OUT_RELU) v = fmaxf(v, 0.f);
            if (OUT_TANH) v = tanhf(v);
            out[obase + c * ostride + (j >> 1) * (long)Wout + (j & 1)] = v;
        }
    }
}

// numpy pairwise sum-of-squares over 64 fp32 values.
__device__ __forceinline__ float np_sumsq64(const float* v) {
    float r[8];
    #pragma unroll
    for (int j = 0; j < 8; j++) r[j] = __fmul_rn(v[j], v[j]);
    #pragma unroll
    for (int i = 8; i < 64; i += 8) {
        #pragma unroll
        for (int j = 0; j < 8; j++)
            r[j] = __fadd_rn(r[j], __fmul_rn(v[i + j], v[i + j]));
    }
    float s01 = __fadd_rn(r[0], r[1]), s23 = __fadd_rn(r[2], r[3]);
    float s45 = __fadd_rn(r[4], r[5]), s67 = __fadd_rn(r[6], r[7]);
    return __fadd_rn(__fadd_rn(s01, s23), __fadd_rn(s45, s67));
}

__global__ void codenorm_kernel(const float* __restrict__ cb, float* __restrict__ cn)
{
    int k = blockIdx.x * 64 + threadIdx.x;
    if (k >= 512) return;
    float row[64];
    #pragma unroll
    for (int d = 0; d < 64; d++) row[d] = cb[k * 64 + d];
    cn[k] = np_sumsq64(row);
}

// VQ: np-exact fp32 chain; st = fl(z + fl(q-z)). As R22/R24 (passing).
__global__ __launch_bounds__(256)
void vq_kernel(const float* __restrict__ z, const float* __restrict__ cb,
               const float* __restrict__ cn, float* __restrict__ st,
               double* __restrict__ loss_sum, int B)
{
    __shared__ float zt[64][64];
    __shared__ float bd[3][64];
    __shared__ int   bk[3][64];
    int t = threadIdx.x;
    long pg = (long)blockIdx.x * 64;
    int b  = (int)(pg >> 12);
    int p0 = (int)(pg & 4095);
    const float* zb = z + (long)b * 64 * 4096 + p0;
    for (int e = t; e < 64 * 64; e += 256) {
        int d = e >> 6, px = e & 63;
        zt[d][px] = zb[(long)d * 4096 + px];
    }
    __syncthreads();

    int px = t & 63;
    int h  = t >> 6;
    float zr[64];
    #pragma unroll
    for (int d = 0; d < 64; d++) zr[d] = zt[d][px];

    float s1 = np_sumsq64(zr);

    float best = INFINITY;
    int bi = 0;
    int k0 = h << 7;
    for (int k = k0; k < k0 + 128; k += 4) {
        const float* c0 = cb + (k + 0) * 64;
        const float* c1 = cb + (k + 1) * 64;
        const float* c2 = cb + (k + 2) * 64;
        const float* c3 = cb + (k + 3) * 64;
        float m0 = 0.f, m1 = 0.f, m2 = 0.f, m3 = 0.f;
        #pragma unroll
        for (int d = 0; d < 64; d++) {
            float zd = zr[d];
            m0 = fmaf(zd, c0[d], m0);
            m1 = fmaf(zd, c1[d], m1);
            m2 = fmaf(zd, c2[d], m2);
            m3 = fmaf(zd, c3[d], m3);
        }
        float d0 = __fadd_rn(__fsub_rn(s1, __fmul_rn(2.f, m0)), cn[k + 0]);
        float d1 = __fadd_rn(__fsub_rn(s1, __fmul_rn(2.f, m1)), cn[k + 1]);
        float d2 = __fadd_rn(__fsub_rn(s1, __fmul_rn(2.f, m2)), cn[k + 2]);
        float d3 = __fadd_rn(__fsub_rn(s1, __fmul_rn(2.f, m3)), cn[k + 3]);
        if (d0 < best) { best = d0; bi = k + 0; }
        if (d1 < best) { best = d1; bi = k + 1; }
        if (d2 < best) { best = d2; bi = k + 2; }
        if (d3 < best) { best = d3; bi = k + 3; }
    }

    if (h) { bd[h - 1][px] = best; bk[h - 1][px] = bi; }
    __syncthreads();
    if (h == 0) {
        #pragma unroll
        for (int j = 0; j < 3; j++) {
            float dj = bd[j][px];
            if (dj < best) { best = dj; bi = bk[j][px]; }
        }
        const float* cbest = cb + bi * 64;
        float* sp = st + (long)b * 64 * 4096 + (p0 + px);
        double ls = 0.0;
        #pragma unroll
        for (int d = 0; d < 64; d++) {
            float qv = cbest[d];
            float zv = zr[d];
            float diff = __fsub_rn(qv, zv);
            double dd = (double)qv - (double)zv;
            ls += dd * dd;
            sp[(long)d * 4096] = __fadd_rn(zv, diff);
        }
        #pragma unroll
        for (int off = 32; off > 0; off >>= 1) ls += __shfl_down(ls, off, 64);
        if (px == 0) atomicAdd(loss_sum, ls);
    }
}

__global__ void loss_final_kernel(const double* __restrict__ s, float* __restrict__ out)
{
    out[0] = (float)(1.25 * s[0] / 8388608.0);   // fp32 loss store
}

extern "C" void kernel_launch(void* const* d_in, const int* in_sizes, int n_in,
                              void* d_out, int out_size, void* d_ws, size_t ws_size,
                              hipStream_t stream)
{
    const float* x        = (const float*)d_in[0];
    const float* enc_w1   = (const float*)d_in[1];
    const float* enc_b1   = (const float*)d_in[2];
    const float* enc_w2   = (const float*)d_in[3];
    const float* enc_b2   = (const float*)d_in[4];
    const float* enc_w3   = (const float*)d_in[5];
    const float* enc_b3   = (const float*)d_in[6];
    const float* enc_rw1  = (const float*)d_in[7];
    const float* enc_rb1  = (const float*)d_in[8];
    const float* enc_rw2  = (const float*)d_in[9];
    const float* enc_rb2  = (const float*)d_in[10];
    const float* pvq_w    = (const float*)d_in[11];
    const float* pvq_b    = (const float*)d_in[12];
    const float* codebook = (const float*)d_in[13];
    const float* dec_w1   = (const float*)d_in[14];
    const float* dec_b1   = (const float*)d_in[15];
    const float* dec_rw1  = (const float*)d_in[16];
    const float* dec_rb1  = (const float*)d_in[17];
    const float* dec_rw2  = (const float*)d_in[18];
    const float* dec_rb2  = (const float*)d_in[19];
    const float* dt1_w    = (const float*)d_in[20];
    const float* dt1_b    = (const float*)d_in[21];
    const float* dt2_w    = (const float*)d_in[22];
    const float* dt2_b    = (const float*)d_in[23];

    float* out = (float*)d_out;            // fp32 output buffer (ref dtype)
    char* wsb = (char*)d_ws;

    float*  CN = (float*)wsb;              // 512 floats
    double* LS = (double*)(wsb + 4096);    // 1 double
    const size_t SMALLB = 4352;

    // Aliased layout, 12 MB/sample (as R21/R22/R24).
    const size_t perSampleB = 12582912;

    int Bc = 32;
    while (Bc > 1 && SMALLB + perSampleB * Bc + 1024 > ws_size) Bc >>= 1;
    const int nChunks = 32 / Bc;

    char* base  = wsb + SMALLB;
    char* qbase = base + (size_t)Bc * 8388608;
    double* A64 = (double*)base;                              // Bc x 1048576 d
    double* C64 = (double*)base;                              // Bc x 524288 d
    double* T64 = (double*)(base + (size_t)Bc * 4194304);     // Bc x 131072 d
    float*  Z32 = (float*)(base + (size_t)Bc * 5242880);      // Bc x 262144 f
    float*  Qf  = (float*)(base + (size_t)Bc * 6291456);      // Bc x 262144 f
    float*  Ef  = (float*)base;                               // Bc x 1048576 f
    double* B64 = (double*)qbase;                             // Bc x 524288 d
    float*  Df  = (float*)qbase;                              // Bc x 524288 f
    float*  Tf  = (float*)(qbase + (size_t)Bc * 2097152);     // Bc x 131072 f

    hipMemsetAsync(LS, 0, sizeof(double), stream);
    codenorm_kernel<<<8, 64, 0, stream>>>(codebook, CN);

    for (int c = 0; c < nChunks; c++) {
        const float* xc = x + (long)c * Bc * 3 * 65536;
        float* outc = out + (long)c * Bc * 3 * 65536;

        // ---- encoder (fp64 accumulate -> fp32 z) ----
        conv_tiled<float,double,double,4,2,1,false,true,false,3,32>
            <<<Bc*8*8*2, 256, 0, stream>>>(
            xc, enc_w1, enc_b1, nullptr, A64, Bc, 3, 256, 256, 64, 128, 128);
        conv_tiled<double,double,double,4,2,1,false,true,false,2,16>
            <<<Bc*4*4*8, 256, 0, stream>>>(
            A64, enc_w2, enc_b2, nullptr, B64, Bc, 64, 128, 128, 128, 64, 64);
        conv_tiled<double,double,double,3,1,1,false,false,false,4,16>
            <<<Bc*4*4*8, 256, 0, stream>>>(
            B64, enc_w3, enc_b3, nullptr, C64, Bc, 128, 64, 64, 128, 64, 64);
        for (int i = 0; i < 2; i++) {
            conv_tiled<double,double,double,3,1,1,true,false,false,8,8>
                <<<Bc*4*4*4, 256, 0, stream>>>(
                C64, enc_rw1 + (long)i*32*128*9, enc_rb1 + i*32, nullptr, T64,
                Bc, 128, 64, 64, 32, 64, 64);
            conv_tiled<double,double,double,1,1,0,true,false,true,8,16>
                <<<Bc*4*4*8, 256, 0, stream>>>(
                T64, enc_rw2 + (long)i*128*32, enc_rb2 + i*128, C64, C64,
                Bc, 32, 64, 64, 128, 64, 64);
        }
        conv_tiled<double,double,float,1,1,0,true,false,false,8,16>
            <<<Bc*4*4*4, 256, 0, stream>>>(
            C64, pvq_w, pvq_b, nullptr, Z32, Bc, 128, 64, 64, 64, 64, 64);

        // ---- VQ (np-exact fp32) ----
        vq_kernel<<<Bc * 64, 256, 0, stream>>>(Z32, codebook, CN, Qf, LS, Bc);

        // ---- decoder (fp32), fp32 output stores ----
        conv_tiled<float,float,float,3,1,1,false,false,false,8,16>
            <<<Bc*4*4*8, 256, 0, stream>>>(
            Qf, dec_w1, dec_b1, nullptr, Df, Bc, 64, 64, 64, 128, 64, 64);
        for (int i = 0; i < 2; i++) {
            conv_tiled<float,float,float,3,1,1,true,false,false,8,8>
                <<<Bc*4*4*4, 256, 0, stream>>>(
                Df, dec_rw1 + (long)i*32*128*9, dec_rb1 + i*32, nullptr, Tf,
                Bc, 128, 64, 64, 32, 64, 64);
            conv_tiled<float,float,float,1,1,0,true,false,true,16,16>
                <<<Bc*4*4*8, 256, 0, stream>>>(
                Tf, dec_rw2 + (long)i*128*32, dec_rb2 + i*128, Df, Df,
                Bc, 32, 64, 64, 128, 64, 64);
        }
        deconv_tiled<8,true,true,false,8><<<Bc*4*4*8, 256, 0, stream>>>(
            Df, dt1_w, dt1_b, Ef, Bc, 128, 64, 64, 64);
        deconv_tiled<3,false,false,true,8><<<Bc*8*8*1, 256, 0, stream>>>(
            Ef, dt2_w, dt2_b, outc, Bc, 64, 128, 128, 3);
    }

    loss_final_kernel<<<1, 1, 0, stream>>>(LS, out + 6291456);
}